// Round 8
// baseline (465.172 us; speedup 1.0000x reference)
//
#include <hip/hip_runtime.h>
#include <hip/hip_bf16.h>
#include <hip/hip_fp16.h>

// Problem constants (CrossAttention_17076789969260)
// Inputs: fp32 buffers (bf16-rounded values). Output: fp32 buffer.
#define B_    4
#define TQ    2048
#define TKV   2048
#define DM    1024
#define NH    16
#define NKV   4
#define DK    64

typedef _Float16 f16x8 __attribute__((ext_vector_type(8)));
typedef _Float16 f16x4 __attribute__((ext_vector_type(4)));
typedef float    f32x4 __attribute__((ext_vector_type(4)));
typedef float    f32x16 __attribute__((ext_vector_type(16)));

template <typename T> struct IsHalf { static constexpr bool v = false; };
template <> struct IsHalf<__half> { static constexpr bool v = true; };

__device__ __forceinline__ void store1(float* p, float v) { *p = v; }
__device__ __forceinline__ void store1(__half* p, float v) {
  union { __half h; unsigned short u; } c; c.h = __float2half(v);
  *(unsigned short*)p = c.u;
}

// pack two fp32 -> 2 x f16 dword (RTZ), type-safe across ROCm versions
__device__ __forceinline__ unsigned pack2h(float a, float b) {
  auto pk = __builtin_amdgcn_cvt_pkrtz(a, b);
  unsigned u;
  __builtin_memcpy(&u, &pk, 4);
  return u;
}

// 4-float fragment load + packed f16 convert (2 x v_cvt_pkrtz)
__device__ __forceinline__ f16x4 load4h(const float* p) {
  float4 v = *(const float4*)p;
  union { unsigned u[2]; f16x4 h; } c;
  c.u[0] = pack2h(v.x, v.y);
  c.u[1] = pack2h(v.z, v.w);
  return c.h;
}

__global__ void zero_out_kernel(float* out, int n) {
  int i = blockIdx.x * blockDim.x + threadIdx.x;
  if (i < n) out[i] = 0.0f;
}

// ---------- MFMA GEMM: C[M,N] = A[M,K] @ W[N,K]^T, f16 MFMA, fp32 acc ----------
// 128x128 tile, BK=32, 4 waves 2x2 (each wave 64x64 = 16 mfma/K-step).
// Double-buffered LDS, register prefetch: per K-step {write regs -> LDS[cur];
// ONE barrier; issue k+1 loads (hide under frag reads + MFMA); read; MFMA}.
// A staging: f16 A uses 16B f16x8 loads + b128 LDS writes (2 passes);
// fp32 A uses float4 + packed cvt (4 passes). W always fp32 (packed cvt).
// ropeT != 0: apply RoPE (period ropeT) to z==0 output in the epilogue
// (pairs (d,d+32) = acc[i][j], acc[i][j+2] in the same thread, fp32 math,
// single f16 rounding) -- fuses the K-rope kernel into the K projection.
// blockIdx.z selects (W0,C0)/(W1,C1) so K/V projections run as one launch.
#define GAP 40
#define RLOG2 -0.41524101186091403f  // -log2(10000)/32
template <typename AT, typename CT>
__global__ __launch_bounds__(256) void gemm_bt_mfma(
    const AT* __restrict__ A,
    const float* __restrict__ W0, const float* __restrict__ W1,
    CT* __restrict__ C0, CT* __restrict__ C1, int M, int N, int K, int ropeT) {
  __shared__ _Float16 As[2 * 128 * GAP];
  __shared__ _Float16 Ws[2 * 128 * GAP];
  const float* __restrict__ W = (blockIdx.z == 0) ? W0 : W1;
  CT* __restrict__ C = (blockIdx.z == 0) ? C0 : C1;

  const int t = threadIdx.x;
  const int w = t >> 6, l = t & 63;
  const int lm = l & 15, quad = l >> 4;
  const int wm = (w >> 1) * 64, wn = (w & 1) * 64;
  const int m0 = blockIdx.y * 128, n0 = blockIdx.x * 128;

  // staging geometries
  const int srow = t >> 3, scol = (t & 7) * 4;   // fp32: 8 lanes/32-col row
  const int hrow = t >> 2, hcol = (t & 3) * 8;   // f16 : 4 lanes/32-col row

  f32x4 acc[4][4] = {};
  f16x4 av4[4], wv4[4];
  f16x8 av8[2];

  auto loadA = [&](int k0) {
    if constexpr (IsHalf<AT>::v) {
#pragma unroll
      for (int p = 0; p < 2; ++p)
        av8[p] = *(const f16x8*)&A[(size_t)(m0 + hrow + p * 64) * K + k0 + hcol];
    } else {
#pragma unroll
      for (int p = 0; p < 4; ++p)
        av4[p] = load4h(&A[(size_t)(m0 + srow + p * 32) * K + k0 + scol]);
    }
  };
  auto storeA = [&](_Float16* as) {
    if constexpr (IsHalf<AT>::v) {
#pragma unroll
      for (int p = 0; p < 2; ++p)
        *(f16x8*)&as[(hrow + p * 64) * GAP + hcol] = av8[p];
    } else {
#pragma unroll
      for (int p = 0; p < 4; ++p)
        *(f16x4*)&as[(srow + p * 32) * GAP + scol] = av4[p];
    }
  };
  auto loadW = [&](int k0) {
#pragma unroll
    for (int p = 0; p < 4; ++p)
      wv4[p] = load4h(&W[(size_t)(n0 + srow + p * 32) * K + k0 + scol]);
  };
  auto storeW = [&](_Float16* ws) {
#pragma unroll
    for (int p = 0; p < 4; ++p)
      *(f16x4*)&ws[(srow + p * 32) * GAP + scol] = wv4[p];
  };

  loadA(0);
  loadW(0);
  int cur = 0;
  for (int k0 = 0; k0 < K; k0 += 32) {
    _Float16* as = &As[cur * 128 * GAP];
    _Float16* ws = &Ws[cur * 128 * GAP];
    storeA(as);
    storeW(ws);
    __syncthreads();
    if (k0 + 32 < K) { loadA(k0 + 32); loadW(k0 + 32); }

    f16x8 af[4], bf[4];
#pragma unroll
    for (int i = 0; i < 4; ++i)
      af[i] = *(const f16x8*)&as[(wm + i * 16 + lm) * GAP + quad * 8];
#pragma unroll
    for (int j = 0; j < 4; ++j)
      bf[j] = *(const f16x8*)&ws[(wn + j * 16 + lm) * GAP + quad * 8];
#pragma unroll
    for (int i = 0; i < 4; ++i)
#pragma unroll
      for (int j = 0; j < 4; ++j)
        acc[i][j] =
            __builtin_amdgcn_mfma_f32_16x16x32_f16(af[i], bf[j], acc[i][j], 0, 0, 0);
    cur ^= 1;
  }

  // fused RoPE (K projection, z==0): col = n0+wn+j*16+lm, d = j*16+lm < 32
  // for j<2; pair at j+2. position = row % ropeT (ropeT is a power of 2).
  if (ropeT != 0 && blockIdx.z == 0) {
    float inv0 = exp2f((float)lm * RLOG2);
    float inv1 = exp2f((float)(16 + lm) * RLOG2);
#pragma unroll
    for (int i = 0; i < 4; ++i)
#pragma unroll
      for (int r = 0; r < 4; ++r) {
        int row = m0 + wm + i * 16 + quad * 4 + r;
        float tpos = (float)(row & (ropeT - 1));
        float c0, s0, c1, s1;
        sincosf(tpos * inv0, &s0, &c0);
        sincosf(tpos * inv1, &s1, &c1);
        float x0 = acc[i][0][r], y0 = acc[i][2][r];
        acc[i][0][r] = x0 * c0 - y0 * s0;
        acc[i][2][r] = y0 * c0 + x0 * s0;
        float x1 = acc[i][1][r], y1 = acc[i][3][r];
        acc[i][1][r] = x1 * c1 - y1 * s1;
        acc[i][3][r] = y1 * c1 + x1 * s1;
      }
  }

  // C/D frag: lane holds D[row=quad*4+r][col=lm] per 16x16 tile
#pragma unroll
  for (int i = 0; i < 4; ++i)
#pragma unroll
    for (int r = 0; r < 4; ++r) {
      size_t row = (size_t)(m0 + wm + i * 16 + quad * 4 + r) * N;
#pragma unroll
      for (int j = 0; j < 4; ++j)
        store1(&C[row + n0 + wn + j * 16 + lm], acc[i][j][r]);
    }
}

// ---------- MFMA flash attention, 32x32 frags, swapped QK^T ----------
// Block = 4 waves (256 thr) = 128 q rows; wave w owns rows [qt*128+w*32, +32).
// mfma_f32_32x32x16_f16 layouts:
//   A-frag: lane holds A[m=lane&31][k=8*(lane>>5)+j], j=0..7
//   B-frag: lane holds B[k=8*(lane>>5)+j][n=lane&31]
//   C/D   : lane holds D[row=(reg&3)+8*(reg>>2)+4*(lane>>5)][col=lane&31]
// Swapped QK^T: st = mfma(A=K, B=Q) = S^T[key][q]; each lane holds 32 scores
// of column q=lane&31 -> row-max is in-lane reduce + one shfl_xor(32).
// P stays in REGISTERS: cvt_pkrtz pack -> one half-swap (shfl_xor 32) per
// dword-pair redistributes into PV A-frags (P[q][key]); no P LDS buffer.
// l = row-sums via ones-B-frag MFMA (row space, matches o_acc).
// Defer-rescale (T13, THR=8 -> P<=256, f16-safe).
// Q-RoPE fused (and 0.125*log2e scale folded into Q): softmax fully base-2.
// __launch_bounds__(256,4): 4 blocks/CU (grid = 1024 = 4*256, one full batch).
// O aliases Q safely: wave reads only its own q rows first, writes them last.
#define AP 72  // LDS pitch (f16): 144B rows -> b128-aligned, balanced banks
#define C2 0.18033688011112042f  // 0.125 * log2(e)
__global__ __launch_bounds__(256, 4) void attn_mfma(const __half* Q,
                                                    const __half* __restrict__ K,
                                                    const __half* __restrict__ V,
                                                    __half* O) {
  __shared__ _Float16 Ks[64 * AP];        // [key][d]
  __shared__ _Float16 Vt[64 * AP];        // [d][key]
  const int t = threadIdx.x;
  const int w = t >> 6, l = t & 63;
  const int lq = l & 31, hi = l >> 5;
  const int qt = blockIdx.x, h = blockIdx.y, b = blockIdx.z;
  const int kvh = h >> 2;

  // Q B-frags (registers, whole kernel): aq[kc] = Q[qrow][kc*16+8*hi+j]
  const __half* qbase =
      Q + (((size_t)b * TQ + qt * 128 + w * 32 + lq) * NH + h) * DK;
  f16x8 aq[4];
#pragma unroll
  for (int kc = 0; kc < 4; ++kc)
    aq[kc] = *(const f16x8*)(qbase + kc * 16 + hi * 8);

  // fused RoPE on Q (in-register) + fold C2 scale: pair (d, d+32) =
  // (aq[kc][j], aq[kc+2][j]); after this, S^T is directly base-2 scores.
  {
    const float tpos = (float)(qt * 128 + w * 32 + lq);
#pragma unroll
    for (int kc = 0; kc < 2; ++kc)
#pragma unroll
      for (int j = 0; j < 8; ++j) {
        int d = kc * 16 + hi * 8 + j;
        float inv = exp2f((float)d * RLOG2);
        float ang = tpos * inv;
        float c, s;
        sincosf(ang, &s, &c);
        float x1 = (float)aq[kc][j], x2 = (float)aq[kc + 2][j];
        aq[kc][j]     = (_Float16)((x1 * c - x2 * s) * C2);
        aq[kc + 2][j] = (_Float16)((x2 * c + x1 * s) * C2);
      }
  }

  const f16x8 vones = {1.f16, 1.f16, 1.f16, 1.f16, 1.f16, 1.f16, 1.f16, 1.f16};

  // staging: 2 x 16B units per thread for K and V each (64x64 f16 tiles)
  const int skey = t >> 3, sdseg = t & 7;          // K [key][d], +32 keys r=1
  const int vkey = t & 63, vdb0 = (t >> 6) * 8;    // V -> Vt [d][key], +32 d r=1
  const __half* kp0 =
      K + (((size_t)b * TKV + skey) * NKV + kvh) * DK + sdseg * 8;
  const __half* kp1 = kp0 + (size_t)32 * NKV * DK;
  const __half* vp0 =
      V + (((size_t)b * TKV + vkey) * NKV + kvh) * DK + vdb0;
  const __half* vp1 = vp0 + 32;
  const size_t kstep = (size_t)64 * NKV * DK;  // 64 keys forward

  f16x8 kpre0 = *(const f16x8*)kp0, kpre1 = *(const f16x8*)kp1;
  f16x8 vpre0 = *(const f16x8*)vp0, vpre1 = *(const f16x8*)vp1;

  f32x16 o_acc[2], l_acc;
#pragma unroll
  for (int i = 0; i < 16; ++i) { o_acc[0][i] = 0.f; o_acc[1][i] = 0.f; l_acc[i] = 0.f; }
  float m_run = -1e30f;

  for (int ck = 0; ck < TKV / 64; ++ck) {
    __syncthreads();  // prior chunk's Ks/Vt reads done
    *(f16x8*)&Ks[skey * AP + sdseg * 8] = kpre0;
    *(f16x8*)&Ks[(skey + 32) * AP + sdseg * 8] = kpre1;
#pragma unroll
    for (int j = 0; j < 8; ++j) {
      Vt[(vdb0 + j) * AP + vkey] = vpre0[j];
      Vt[(vdb0 + 32 + j) * AP + vkey] = vpre1[j];
    }
    __syncthreads();
    // T14: issue next chunk's loads now; latency hides under compute below
    if (ck + 1 < TKV / 64) {
      size_t off = (size_t)(ck + 1) * kstep;
      kpre0 = *(const f16x8*)(kp0 + off);
      kpre1 = *(const f16x8*)(kp1 + off);
      vpre0 = *(const f16x8*)(vp0 + off);
      vpre1 = *(const f16x8*)(vp1 + off);
    }

    // S^T = K Q^T : st[tile] covers keys [tile*32, +32) x 32 q-cols
    f32x16 st[2];
#pragma unroll
    for (int i = 0; i < 16; ++i) { st[0][i] = 0.f; st[1][i] = 0.f; }
    __builtin_amdgcn_s_setprio(1);
#pragma unroll
    for (int tile = 0; tile < 2; ++tile)
#pragma unroll
      for (int kc = 0; kc < 4; ++kc) {
        f16x8 ak =
            *(const f16x8*)&Ks[(tile * 32 + lq) * AP + kc * 16 + hi * 8];
        st[tile] =
            __builtin_amdgcn_mfma_f32_32x32x16_f16(ak, aq[kc], st[tile], 0, 0, 0);
      }
    __builtin_amdgcn_s_setprio(0);

    // column max (q = lane&31): in-lane over 32 regs, then swap halves
    float vmax = st[0][0];
#pragma unroll
    for (int i = 1; i < 16; ++i) vmax = fmaxf(vmax, st[0][i]);
#pragma unroll
    for (int i = 0; i < 16; ++i) vmax = fmaxf(vmax, st[1][i]);
    vmax = fmaxf(vmax, __shfl_xor(vmax, 32));

    // T13 defer-rescale: only pay when max grew past THR
    if (!__all(vmax - m_run <= 8.0f)) {
      float m_new = fmaxf(m_run, vmax);
      float alpha = exp2f(m_run - m_new);  // column space (q = lane&31)
      m_run = m_new;
#pragma unroll
      for (int reg = 0; reg < 16; ++reg) {
        int row = (reg & 3) + 8 * (reg >> 2) + 4 * hi;
        float ar = __shfl(alpha, row);     // alpha for q-row of this reg
        l_acc[reg] *= ar;
        o_acc[0][reg] *= ar;
        o_acc[1][reg] *= ar;
      }
    }

    // P = 2^(st - m), packed to f16 pairs (consecutive keys)
    unsigned q16u[2][8];
#pragma unroll
    for (int tile = 0; tile < 2; ++tile)
#pragma unroll
      for (int rr = 0; rr < 8; ++rr) {
        float p0 = exp2f(st[tile][2 * rr] - m_run);
        float p1 = exp2f(st[tile][2 * rr + 1] - m_run);
        q16u[tile][rr] = pack2h(p0, p1);
      }

    // Redistribute P^T (column space) -> PV A-frags (row space) and O += P V.
    __builtin_amdgcn_s_setprio(1);
#pragma unroll
    for (int kb = 0; kb < 4; ++kb) {
      const int tl = kb >> 1, base = (kb & 1) * 4;
      union { unsigned u[4]; f16x8 v; } ap;
#pragma unroll
      for (int c = 0; c < 2; ++c) {
        unsigned R0 = q16u[tl][base + c];       // reg wanted by hi_t=0
        unsigned R1 = q16u[tl][base + 2 + c];   // reg wanted by hi_t=1
        unsigned Z = hi ? R0 : R1;              // what my partner wants
        unsigned Xp = __shfl_xor(Z, 32);        // partner's Z (what I want)
        ap.u[c]     = hi ? Xp : R0;             // from hi=0 half
        ap.u[c + 2] = hi ? R1 : Xp;             // from hi=1 half
      }
      l_acc = __builtin_amdgcn_mfma_f32_32x32x16_f16(ap.v, vones, l_acc, 0, 0, 0);
#pragma unroll
      for (int nt = 0; nt < 2; ++nt) {
        f16x8 bv = *(const f16x8*)&Vt[(nt * 32 + lq) * AP + kb * 16 + hi * 8];
        o_acc[nt] =
            __builtin_amdgcn_mfma_f32_32x32x16_f16(ap.v, bv, o_acc[nt], 0, 0, 0);
      }
    }
    __builtin_amdgcn_s_setprio(0);
  }

  // epilogue: row = (reg&3)+8*(reg>>2)+4*hi, cols d = nt*32 + lq
#pragma unroll
  for (int reg = 0; reg < 16; ++reg) {
    int row = (reg & 3) + 8 * (reg >> 2) + 4 * hi;
    float inv = 1.0f / l_acc[reg];
    size_t orow =
        (((size_t)b * TQ + qt * 128 + w * 32 + row) * NH + h) * DK;
    O[orow + lq]      = __float2half(o_acc[0][reg] * inv);
    O[orow + 32 + lq] = __float2half(o_acc[1][reg] * inv);
  }
}

extern "C" void kernel_launch(void* const* d_in, const int* in_sizes, int n_in,
                              void* d_out, int out_size, void* d_ws, size_t ws_size,
                              hipStream_t stream) {
  // ---- Input mapping via in_sizes pattern (dict vs sorted-key order) ----
  int iq, ikv, iwq, iwk, iwv, iwo;
  bool ok = true;
  if (n_in >= 8 && in_sizes[0] == 8388608 && in_sizes[1] == 8388608) {
    iq = 0; ikv = 1; iwq = 4; iwk = 5; iwv = 6; iwo = 7;          // dict order
  } else if (n_in >= 8 && in_sizes[0] == 8388608 && in_sizes[1] == 8192) {
    ikv = 0; iq = 2; iwk = 4; iwo = 5; iwq = 6; iwv = 7;          // sorted keys
  } else if (n_in == 6 && in_sizes[2] == 1048576) {
    iq = 0; ikv = 1; iwq = 2; iwk = 3; iwv = 4; iwo = 5;          // dict, no masks
  } else if (n_in == 6 && in_sizes[2] == 262144) {
    ikv = 0; iq = 1; iwk = 2; iwo = 3; iwq = 4; iwv = 5;          // sorted, no masks
  } else {
    ok = false; iq = ikv = iwq = iwk = iwv = iwo = 0;
  }

  const size_t nQ  = (size_t)B_ * TQ * DM;
  const size_t nKV = (size_t)B_ * TKV * NKV * DK;
  const size_t need = (nQ + 2 * nKV) * sizeof(__half);  // 24 MB
  if (!ok || ws_size < need) {
    zero_out_kernel<<<(out_size + 255) / 256, 256, 0, stream>>>((float*)d_out,
                                                                out_size);
    return;
  }

  const float* query     = (const float*)d_in[iq];
  const float* key_value = (const float*)d_in[ikv];
  const float* w_q   = (const float*)d_in[iwq];
  const float* w_k   = (const float*)d_in[iwk];
  const float* w_v   = (const float*)d_in[iwv];
  const float* w_out = (const float*)d_in[iwo];
  float* out = (float*)d_out;

  __half* Qh = (__half*)d_ws;
  __half* Kh = Qh + nQ;
  __half* Vh = Kh + nKV;

  dim3 blk(256);
  // Q projection: M=8192, N=1024, K=1024 (Q-rope fused into attn)
  gemm_bt_mfma<<<dim3(DM / 128, B_ * TQ / 128, 1), blk, 0, stream>>>(
      query, w_q, w_q, Qh, Qh, B_ * TQ, DM, DM, 0);
  // K and V projections fused in one launch (z selects weight/output);
  // K-rope fused into the z==0 epilogue (ropeT = TKV).
  gemm_bt_mfma<<<dim3(NKV * DK / 128, B_ * TKV / 128, 2), blk, 0, stream>>>(
      key_value, w_k, w_v, Kh, Vh, B_ * TKV, NKV * DK, DM, TKV);
  // MFMA flash attention (32x32 frags, P-in-register, fused Q-rope)
  attn_mfma<<<dim3(TQ / 128, NH, B_), dim3(256), 0, stream>>>(Qh, Kh, Vh, Qh);
  // Output projection: M=8192, N=1024, K=1024, fp32 out (f16 A, wide staging)
  gemm_bt_mfma<<<dim3(DM / 128, B_ * TQ / 128, 1), blk, 0, stream>>>(
      Qh, w_out, w_out, out, out, B_ * TQ, DM, DM, 0);
}

// Round 9
// 449.717 us; speedup vs baseline: 1.0344x; 1.0344x over previous
//
#include <hip/hip_runtime.h>
#include <hip/hip_bf16.h>
#include <hip/hip_fp16.h>

// Problem constants (CrossAttention_17076789969260)
// Inputs: fp32 buffers (bf16-rounded values). Output: fp32 buffer.
#define B_    4
#define TQ    2048
#define TKV   2048
#define DM    1024
#define NH    16
#define NKV   4
#define DK    64

typedef _Float16 f16x8 __attribute__((ext_vector_type(8)));
typedef _Float16 f16x4 __attribute__((ext_vector_type(4)));
typedef float    f32x4 __attribute__((ext_vector_type(4)));
typedef float    f32x16 __attribute__((ext_vector_type(16)));

template <typename T> struct IsHalf { static constexpr bool v = false; };
template <> struct IsHalf<__half> { static constexpr bool v = true; };

__device__ __forceinline__ void store1(float* p, float v) { *p = v; }
__device__ __forceinline__ void store1(__half* p, float v) {
  union { __half h; unsigned short u; } c; c.h = __float2half(v);
  *(unsigned short*)p = c.u;
}

// pack two fp32 -> 2 x f16 dword (RTZ), type-safe across ROCm versions
__device__ __forceinline__ unsigned pack2h(float a, float b) {
  auto pk = __builtin_amdgcn_cvt_pkrtz(a, b);
  unsigned u;
  __builtin_memcpy(&u, &pk, 4);
  return u;
}

// 4-float fragment load + packed f16 convert (2 x v_cvt_pkrtz)
__device__ __forceinline__ f16x4 load4h(const float* p) {
  float4 v = *(const float4*)p;
  union { unsigned u[2]; f16x4 h; } c;
  c.u[0] = pack2h(v.x, v.y);
  c.u[1] = pack2h(v.z, v.w);
  return c.h;
}

__global__ void zero_out_kernel(float* out, int n) {
  int i = blockIdx.x * blockDim.x + threadIdx.x;
  if (i < n) out[i] = 0.0f;
}

// ---------- MFMA GEMM: C[M,N] = A[M,K] @ W[N,K]^T, f16 MFMA, fp32 acc ----------
// 128x128 tile, BK=32, 4 waves 2x2 (each wave 64x64 = 16 mfma/K-step).
// Double-buffered LDS, register prefetch: per K-step {write regs -> LDS[cur];
// ONE barrier; issue k+1 loads (hide under frag reads + MFMA); read; MFMA}.
// A staging: f16 A uses 16B f16x8 loads + b128 LDS writes (2 passes);
// fp32 A uses float4 + packed cvt (4 passes). W always fp32 (packed cvt).
// ropeT != 0: apply RoPE (period ropeT) to z==0 output in the epilogue
// (pairs (d,d+32) = acc[i][j], acc[i][j+2] in the same thread, fp32 math,
// single f16 rounding) -- fuses the K-rope kernel into the K projection.
// blockIdx.z selects (W0,C0)/(W1,C1) so K/V projections run as one launch.
#define GAP 40
#define RLOG2 -0.41524101186091403f  // -log2(10000)/32
template <typename AT, typename CT>
__global__ __launch_bounds__(256) void gemm_bt_mfma(
    const AT* __restrict__ A,
    const float* __restrict__ W0, const float* __restrict__ W1,
    CT* __restrict__ C0, CT* __restrict__ C1, int M, int N, int K, int ropeT) {
  __shared__ _Float16 As[2 * 128 * GAP];
  __shared__ _Float16 Ws[2 * 128 * GAP];
  const float* __restrict__ W = (blockIdx.z == 0) ? W0 : W1;
  CT* __restrict__ C = (blockIdx.z == 0) ? C0 : C1;

  const int t = threadIdx.x;
  const int w = t >> 6, l = t & 63;
  const int lm = l & 15, quad = l >> 4;
  const int wm = (w >> 1) * 64, wn = (w & 1) * 64;
  const int m0 = blockIdx.y * 128, n0 = blockIdx.x * 128;

  // staging geometries
  const int srow = t >> 3, scol = (t & 7) * 4;   // fp32: 8 lanes/32-col row
  const int hrow = t >> 2, hcol = (t & 3) * 8;   // f16 : 4 lanes/32-col row

  f32x4 acc[4][4] = {};
  f16x4 av4[4], wv4[4];
  f16x8 av8[2];

  auto loadA = [&](int k0) {
    if constexpr (IsHalf<AT>::v) {
#pragma unroll
      for (int p = 0; p < 2; ++p)
        av8[p] = *(const f16x8*)&A[(size_t)(m0 + hrow + p * 64) * K + k0 + hcol];
    } else {
#pragma unroll
      for (int p = 0; p < 4; ++p)
        av4[p] = load4h(&A[(size_t)(m0 + srow + p * 32) * K + k0 + scol]);
    }
  };
  auto storeA = [&](_Float16* as) {
    if constexpr (IsHalf<AT>::v) {
#pragma unroll
      for (int p = 0; p < 2; ++p)
        *(f16x8*)&as[(hrow + p * 64) * GAP + hcol] = av8[p];
    } else {
#pragma unroll
      for (int p = 0; p < 4; ++p)
        *(f16x4*)&as[(srow + p * 32) * GAP + scol] = av4[p];
    }
  };
  auto loadW = [&](int k0) {
#pragma unroll
    for (int p = 0; p < 4; ++p)
      wv4[p] = load4h(&W[(size_t)(n0 + srow + p * 32) * K + k0 + scol]);
  };
  auto storeW = [&](_Float16* ws) {
#pragma unroll
    for (int p = 0; p < 4; ++p)
      *(f16x4*)&ws[(srow + p * 32) * GAP + scol] = wv4[p];
  };

  loadA(0);
  loadW(0);
  int cur = 0;
  for (int k0 = 0; k0 < K; k0 += 32) {
    _Float16* as = &As[cur * 128 * GAP];
    _Float16* ws = &Ws[cur * 128 * GAP];
    storeA(as);
    storeW(ws);
    __syncthreads();
    if (k0 + 32 < K) { loadA(k0 + 32); loadW(k0 + 32); }

    f16x8 af[4], bf[4];
#pragma unroll
    for (int i = 0; i < 4; ++i)
      af[i] = *(const f16x8*)&as[(wm + i * 16 + lm) * GAP + quad * 8];
#pragma unroll
    for (int j = 0; j < 4; ++j)
      bf[j] = *(const f16x8*)&ws[(wn + j * 16 + lm) * GAP + quad * 8];
#pragma unroll
    for (int i = 0; i < 4; ++i)
#pragma unroll
      for (int j = 0; j < 4; ++j)
        acc[i][j] =
            __builtin_amdgcn_mfma_f32_16x16x32_f16(af[i], bf[j], acc[i][j], 0, 0, 0);
    cur ^= 1;
  }

  // fused RoPE (K projection, z==0): col = n0+wn+j*16+lm, d = j*16+lm < 32
  // for j<2; pair at j+2. position = row % ropeT (ropeT is a power of 2).
  if (ropeT != 0 && blockIdx.z == 0) {
    float inv0 = exp2f((float)lm * RLOG2);
    float inv1 = exp2f((float)(16 + lm) * RLOG2);
#pragma unroll
    for (int i = 0; i < 4; ++i)
#pragma unroll
      for (int r = 0; r < 4; ++r) {
        int row = m0 + wm + i * 16 + quad * 4 + r;
        float tpos = (float)(row & (ropeT - 1));
        float c0, s0, c1, s1;
        sincosf(tpos * inv0, &s0, &c0);
        sincosf(tpos * inv1, &s1, &c1);
        float x0 = acc[i][0][r], y0 = acc[i][2][r];
        acc[i][0][r] = x0 * c0 - y0 * s0;
        acc[i][2][r] = y0 * c0 + x0 * s0;
        float x1 = acc[i][1][r], y1 = acc[i][3][r];
        acc[i][1][r] = x1 * c1 - y1 * s1;
        acc[i][3][r] = y1 * c1 + x1 * s1;
      }
  }

  // C/D frag: lane holds D[row=quad*4+r][col=lm] per 16x16 tile
#pragma unroll
  for (int i = 0; i < 4; ++i)
#pragma unroll
    for (int r = 0; r < 4; ++r) {
      size_t row = (size_t)(m0 + wm + i * 16 + quad * 4 + r) * N;
#pragma unroll
      for (int j = 0; j < 4; ++j)
        store1(&C[row + n0 + wn + j * 16 + lm], acc[i][j][r]);
    }
}

// ---------- MFMA flash attention, 32x32 frags, swapped QK^T ----------
// Block = 4 waves (256 thr) = 128 q rows; wave w owns rows [qt*128+w*32, +32).
// mfma_f32_32x32x16_f16 layouts:
//   A-frag: lane holds A[m=lane&31][k=8*(lane>>5)+j], j=0..7
//   B-frag: lane holds B[k=8*(lane>>5)+j][n=lane&31]
//   C/D   : lane holds D[row=(reg&3)+8*(reg>>2)+4*(lane>>5)][col=lane&31]
// Swapped QK^T: st = mfma(A=K, B=Q) = S^T[key][q]; lane's 16 regs hold the
// scores of q-column lq for 16 of the tile's 32 keys (other half at lane+32).
// Per-32-key-tile processing (ONE f32x16 st reused; -16 regs vs 2-tile) and
// l_run kept as a COLUMN-SPACE SCALAR (in-lane sum + shfl_xor(32); -16 regs,
// no ones-MFMA) keep the live set ~110 regs -> fits the (256,4) 128-budget
// WITHOUT SPILL (R8's regression: 160-reg live set forced to 64 arch VGPRs).
// P stays in registers: cvt_pkrtz pack -> one half-swap per dword pair into
// PV A-frags. Defer-rescale (T13, THR=8 -> P<=256, f16-safe).
// Q-RoPE fused (+0.125*log2e scale folded into Q): softmax fully base-2.
// O aliases Q safely: wave reads only its own q rows first, writes them last.
#define AP 72  // LDS pitch (f16): 144B rows -> b128-aligned, balanced banks
#define C2 0.18033688011112042f  // 0.125 * log2(e)
__global__ __launch_bounds__(256, 4) void attn_mfma(const __half* Q,
                                                    const __half* __restrict__ K,
                                                    const __half* __restrict__ V,
                                                    __half* O) {
  __shared__ _Float16 Ks[64 * AP];        // [key][d]
  __shared__ _Float16 Vt[64 * AP];        // [d][key]
  const int t = threadIdx.x;
  const int w = t >> 6, l = t & 63;
  const int lq = l & 31, hi = l >> 5;
  const int qt = blockIdx.x, h = blockIdx.y, b = blockIdx.z;
  const int kvh = h >> 2;

  // Q B-frags (registers, whole kernel): aq[kc] = Q[qrow][kc*16+8*hi+j]
  const __half* qbase =
      Q + (((size_t)b * TQ + qt * 128 + w * 32 + lq) * NH + h) * DK;
  f16x8 aq[4];
#pragma unroll
  for (int kc = 0; kc < 4; ++kc)
    aq[kc] = *(const f16x8*)(qbase + kc * 16 + hi * 8);

  // fused RoPE on Q (in-register) + fold C2 scale: pair (d, d+32) =
  // (aq[kc][j], aq[kc+2][j]); after this, S^T is directly base-2 scores.
  {
    const float tpos = (float)(qt * 128 + w * 32 + lq);
#pragma unroll
    for (int kc = 0; kc < 2; ++kc)
#pragma unroll
      for (int j = 0; j < 8; ++j) {
        int d = kc * 16 + hi * 8 + j;
        float inv = exp2f((float)d * RLOG2);
        float ang = tpos * inv;
        float c, s;
        sincosf(ang, &s, &c);
        float x1 = (float)aq[kc][j], x2 = (float)aq[kc + 2][j];
        aq[kc][j]     = (_Float16)((x1 * c - x2 * s) * C2);
        aq[kc + 2][j] = (_Float16)((x2 * c + x1 * s) * C2);
      }
  }

  // staging: 2 x 16B units per thread for K and V each (64x64 f16 tiles)
  const int skey = t >> 3, sdseg = t & 7;          // K [key][d], +32 keys r=1
  const int vkey = t & 63, vdb0 = (t >> 6) * 8;    // V -> Vt [d][key], +32 d r=1
  const __half* kp0 =
      K + (((size_t)b * TKV + skey) * NKV + kvh) * DK + sdseg * 8;
  const __half* kp1 = kp0 + (size_t)32 * NKV * DK;
  const __half* vp0 =
      V + (((size_t)b * TKV + vkey) * NKV + kvh) * DK + vdb0;
  const __half* vp1 = vp0 + 32;
  const size_t kstep = (size_t)64 * NKV * DK;  // 64 keys forward

  f16x8 kpre0 = *(const f16x8*)kp0, kpre1 = *(const f16x8*)kp1;
  f16x8 vpre0 = *(const f16x8*)vp0, vpre1 = *(const f16x8*)vp1;

  f32x16 o_acc[2];
#pragma unroll
  for (int i = 0; i < 16; ++i) { o_acc[0][i] = 0.f; o_acc[1][i] = 0.f; }
  float m_run = -1e30f, l_run = 0.0f;  // column space (q = lq)

  for (int ck = 0; ck < TKV / 64; ++ck) {
    __syncthreads();  // prior chunk's Ks/Vt reads done
    *(f16x8*)&Ks[skey * AP + sdseg * 8] = kpre0;
    *(f16x8*)&Ks[(skey + 32) * AP + sdseg * 8] = kpre1;
#pragma unroll
    for (int j = 0; j < 8; ++j) {
      Vt[(vdb0 + j) * AP + vkey] = vpre0[j];
      Vt[(vdb0 + 32 + j) * AP + vkey] = vpre1[j];
    }
    __syncthreads();
    // T14: issue next chunk's loads now; latency hides under compute below
    if (ck + 1 < TKV / 64) {
      size_t off = (size_t)(ck + 1) * kstep;
      kpre0 = *(const f16x8*)(kp0 + off);
      kpre1 = *(const f16x8*)(kp1 + off);
      vpre0 = *(const f16x8*)(vp0 + off);
      vpre1 = *(const f16x8*)(vp1 + off);
    }

#pragma unroll
    for (int tile = 0; tile < 2; ++tile) {
      // S^T = K Q^T for keys [tile*32, +32) x 32 q-cols
      f32x16 st;
#pragma unroll
      for (int i = 0; i < 16; ++i) st[i] = 0.f;
      __builtin_amdgcn_s_setprio(1);
#pragma unroll
      for (int kc = 0; kc < 4; ++kc) {
        f16x8 ak =
            *(const f16x8*)&Ks[(tile * 32 + lq) * AP + kc * 16 + hi * 8];
        st = __builtin_amdgcn_mfma_f32_32x32x16_f16(ak, aq[kc], st, 0, 0, 0);
      }
      __builtin_amdgcn_s_setprio(0);

      // column max (q = lq): in-lane over 16 regs, then swap halves
      float vmax = st[0];
#pragma unroll
      for (int i = 1; i < 16; ++i) vmax = fmaxf(vmax, st[i]);
      vmax = fmaxf(vmax, __shfl_xor(vmax, 32));

      // T13 defer-rescale: only pay when max grew past THR
      if (!__all(vmax - m_run <= 8.0f)) {
        float m_new = fmaxf(m_run, vmax);
        float alpha = exp2f(m_run - m_new);  // column space
        m_run = m_new;
        l_run *= alpha;
#pragma unroll
        for (int reg = 0; reg < 16; ++reg) {
          int row = (reg & 3) + 8 * (reg >> 2) + 4 * hi;
          float ar = __shfl(alpha, row);     // alpha for q-row of this reg
          o_acc[0][reg] *= ar;
          o_acc[1][reg] *= ar;
        }
      }

      // P = 2^(st - m): pack to f16 pairs; l_run += column sum
      unsigned q16u[8];
      float psum = 0.0f;
#pragma unroll
      for (int rr = 0; rr < 8; ++rr) {
        float p0 = exp2f(st[2 * rr] - m_run);
        float p1 = exp2f(st[2 * rr + 1] - m_run);
        psum += p0 + p1;
        q16u[rr] = pack2h(p0, p1);
      }
      psum += __shfl_xor(psum, 32);  // other half's 16 keys
      l_run += psum;

      // Redistribute P^T (column space) -> PV A-frags (row space); O += P V
      __builtin_amdgcn_s_setprio(1);
#pragma unroll
      for (int kb = 0; kb < 2; ++kb) {
        const int base = kb * 4;
        union { unsigned u[4]; f16x8 v; } ap;
#pragma unroll
        for (int c = 0; c < 2; ++c) {
          unsigned R0 = q16u[base + c];       // reg wanted by hi_t=0
          unsigned R1 = q16u[base + 2 + c];   // reg wanted by hi_t=1
          unsigned Z = hi ? R0 : R1;          // what my partner wants
          unsigned Xp = __shfl_xor(Z, 32);    // partner's Z (what I want)
          ap.u[c]     = hi ? Xp : R0;         // from hi=0 half
          ap.u[c + 2] = hi ? R1 : Xp;         // from hi=1 half
        }
#pragma unroll
        for (int nt = 0; nt < 2; ++nt) {
          f16x8 bv = *(const f16x8*)&Vt[(nt * 32 + lq) * AP + tile * 32 +
                                        kb * 16 + hi * 8];
          o_acc[nt] =
              __builtin_amdgcn_mfma_f32_32x32x16_f16(ap.v, bv, o_acc[nt], 0, 0, 0);
        }
      }
      __builtin_amdgcn_s_setprio(0);
    }
  }

  // epilogue: row = (reg&3)+8*(reg>>2)+4*hi, cols d = nt*32 + lq;
  // l_run is column-space -> fetch per-row value by lane shuffle.
#pragma unroll
  for (int reg = 0; reg < 16; ++reg) {
    int row = (reg & 3) + 8 * (reg >> 2) + 4 * hi;
    float inv = 1.0f / __shfl(l_run, row);
    size_t orow =
        (((size_t)b * TQ + qt * 128 + w * 32 + row) * NH + h) * DK;
    O[orow + lq]      = __float2half(o_acc[0][reg] * inv);
    O[orow + 32 + lq] = __float2half(o_acc[1][reg] * inv);
  }
}

extern "C" void kernel_launch(void* const* d_in, const int* in_sizes, int n_in,
                              void* d_out, int out_size, void* d_ws, size_t ws_size,
                              hipStream_t stream) {
  // ---- Input mapping via in_sizes pattern (dict vs sorted-key order) ----
  int iq, ikv, iwq, iwk, iwv, iwo;
  bool ok = true;
  if (n_in >= 8 && in_sizes[0] == 8388608 && in_sizes[1] == 8388608) {
    iq = 0; ikv = 1; iwq = 4; iwk = 5; iwv = 6; iwo = 7;          // dict order
  } else if (n_in >= 8 && in_sizes[0] == 8388608 && in_sizes[1] == 8192) {
    ikv = 0; iq = 2; iwk = 4; iwo = 5; iwq = 6; iwv = 7;          // sorted keys
  } else if (n_in == 6 && in_sizes[2] == 1048576) {
    iq = 0; ikv = 1; iwq = 2; iwk = 3; iwv = 4; iwo = 5;          // dict, no masks
  } else if (n_in == 6 && in_sizes[2] == 262144) {
    ikv = 0; iq = 1; iwk = 2; iwo = 3; iwq = 4; iwv = 5;          // sorted, no masks
  } else {
    ok = false; iq = ikv = iwq = iwk = iwv = iwo = 0;
  }

  const size_t nQ  = (size_t)B_ * TQ * DM;
  const size_t nKV = (size_t)B_ * TKV * NKV * DK;
  const size_t need = (nQ + 2 * nKV) * sizeof(__half);  // 24 MB
  if (!ok || ws_size < need) {
    zero_out_kernel<<<(out_size + 255) / 256, 256, 0, stream>>>((float*)d_out,
                                                                out_size);
    return;
  }

  const float* query     = (const float*)d_in[iq];
  const float* key_value = (const float*)d_in[ikv];
  const float* w_q   = (const float*)d_in[iwq];
  const float* w_k   = (const float*)d_in[iwk];
  const float* w_v   = (const float*)d_in[iwv];
  const float* w_out = (const float*)d_in[iwo];
  float* out = (float*)d_out;

  __half* Qh = (__half*)d_ws;
  __half* Kh = Qh + nQ;
  __half* Vh = Kh + nKV;

  dim3 blk(256);
  // Q projection: M=8192, N=1024, K=1024 (Q-rope fused into attn)
  gemm_bt_mfma<<<dim3(DM / 128, B_ * TQ / 128, 1), blk, 0, stream>>>(
      query, w_q, w_q, Qh, Qh, B_ * TQ, DM, DM, 0);
  // K and V projections fused in one launch (z selects weight/output);
  // K-rope fused into the z==0 epilogue (ropeT = TKV).
  gemm_bt_mfma<<<dim3(NKV * DK / 128, B_ * TKV / 128, 2), blk, 0, stream>>>(
      key_value, w_k, w_v, Kh, Vh, B_ * TKV, NKV * DK, DM, TKV);
  // MFMA flash attention (32x32 frags, P-in-register, fused Q-rope)
  attn_mfma<<<dim3(TQ / 128, NH, B_), dim3(256), 0, stream>>>(Qh, Kh, Vh, Qh);
  // Output projection: M=8192, N=1024, K=1024, fp32 out (f16 A, wide staging)
  gemm_bt_mfma<<<dim3(DM / 128, B_ * TQ / 128, 1), blk, 0, stream>>>(
      Qh, w_out, w_out, out, out, B_ * TQ, DM, DM, 0);
}

// Round 10
// 387.821 us; speedup vs baseline: 1.1995x; 1.1596x over previous
//
#include <hip/hip_runtime.h>
#include <hip/hip_bf16.h>
#include <hip/hip_fp16.h>

// Problem constants (CrossAttention_17076789969260)
// Inputs: fp32 buffers (bf16-rounded values). Output: fp32 buffer.
#define B_    4
#define TQ    2048
#define TKV   2048
#define DM    1024
#define NH    16
#define NKV   4
#define DK    64

typedef _Float16 f16x8 __attribute__((ext_vector_type(8)));
typedef _Float16 f16x4 __attribute__((ext_vector_type(4)));
typedef float    f32x4 __attribute__((ext_vector_type(4)));
typedef float    f32x16 __attribute__((ext_vector_type(16)));

__device__ __forceinline__ void store1(float* p, float v) { *p = v; }
__device__ __forceinline__ void store1(__half* p, float v) {
  union { __half h; unsigned short u; } c; c.h = __float2half(v);
  *(unsigned short*)p = c.u;
}

// 4-element fragment loaders for GEMM staging (result: f16x4).
__device__ __forceinline__ f16x4 load4h(const float* p) {
  float4 v = *(const float4*)p;
  f16x4 r;
  r[0] = (_Float16)v.x; r[1] = (_Float16)v.y;
  r[2] = (_Float16)v.z; r[3] = (_Float16)v.w;
  return r;
}
__device__ __forceinline__ f16x4 load4h(const __half* p) {
  return *(const f16x4*)p;  // already f16
}

// pack two fp32 -> 2 x f16 dword (RTZ), type-safe across ROCm versions
__device__ __forceinline__ unsigned pack2h(float a, float b) {
  auto pk = __builtin_amdgcn_cvt_pkrtz(a, b);
  unsigned u;
  __builtin_memcpy(&u, &pk, 4);
  return u;
}

__global__ void zero_out_kernel(float* out, int n) {
  int i = blockIdx.x * blockDim.x + threadIdx.x;
  if (i < n) out[i] = 0.0f;
}

// ---------- MFMA GEMM: C[M,N] = A[M,K] @ W[N,K]^T, f16 MFMA, fp32 acc ----------
// (R7-exact: known-good 238us pool; R8's pack2h/wide-A/ropeT edits regressed)
// 128x128 tile, BK=32, 4 waves 2x2 (each wave 64x64 = 16 mfma/K-step).
// Double-buffered LDS, register prefetch: per K-step {write regs -> LDS[cur];
// ONE barrier; issue k+1 loads (hide under frag reads + MFMA); read; MFMA}.
// Write->Sync->Read order makes single-barrier dbuf race-free (skew <= 1 it).
// fp32->f16 conversion fused into staging (inputs bf16-rounded -> exact).
// blockIdx.z selects (W0,C0)/(W1,C1) so K/V projections run as one launch.
#define GAP 40
template <typename AT, typename CT>
__global__ __launch_bounds__(256) void gemm_bt_mfma(
    const AT* __restrict__ A,
    const float* __restrict__ W0, const float* __restrict__ W1,
    CT* __restrict__ C0, CT* __restrict__ C1, int M, int N, int K) {
  __shared__ _Float16 As[2 * 128 * GAP];
  __shared__ _Float16 Ws[2 * 128 * GAP];
  const float* __restrict__ W = (blockIdx.z == 0) ? W0 : W1;
  CT* __restrict__ C = (blockIdx.z == 0) ? C0 : C1;

  const int t = threadIdx.x;
  const int w = t >> 6, l = t & 63;
  const int lm = l & 15, quad = l >> 4;
  const int wm = (w >> 1) * 64, wn = (w & 1) * 64;
  const int m0 = blockIdx.y * 128, n0 = blockIdx.x * 128;

  // staging: 8 lanes per 32-elem row; 32 rows per pass, 4 passes
  const int srow = t >> 3;        // 0..31
  const int scol = (t & 7) * 4;   // 0,4,..,28

  f32x4 acc[4][4] = {};
  f16x4 av[4], wv[4];
  // prologue: load K-step 0 into regs
#pragma unroll
  for (int p = 0; p < 4; ++p) {
    int r = srow + p * 32;
    av[p] = load4h(&A[(size_t)(m0 + r) * K + scol]);
    wv[p] = load4h(&W[(size_t)(n0 + r) * K + scol]);
  }

  int cur = 0;
  for (int k0 = 0; k0 < K; k0 += 32) {
    _Float16* as = &As[cur * 128 * GAP];
    _Float16* ws = &Ws[cur * 128 * GAP];
#pragma unroll
    for (int p = 0; p < 4; ++p) {
      int r = srow + p * 32;
      *(f16x4*)&as[r * GAP + scol] = av[p];
      *(f16x4*)&ws[r * GAP + scol] = wv[p];
    }
    __syncthreads();
    // issue next K-step's loads; latency hides under frag reads + MFMA
    if (k0 + 32 < K) {
#pragma unroll
      for (int p = 0; p < 4; ++p) {
        int r = srow + p * 32;
        av[p] = load4h(&A[(size_t)(m0 + r) * K + k0 + 32 + scol]);
        wv[p] = load4h(&W[(size_t)(n0 + r) * K + k0 + 32 + scol]);
      }
    }

    f16x8 af[4], bf[4];
#pragma unroll
    for (int i = 0; i < 4; ++i)
      af[i] = *(const f16x8*)&as[(wm + i * 16 + lm) * GAP + quad * 8];
#pragma unroll
    for (int j = 0; j < 4; ++j)
      bf[j] = *(const f16x8*)&ws[(wn + j * 16 + lm) * GAP + quad * 8];
#pragma unroll
    for (int i = 0; i < 4; ++i)
#pragma unroll
      for (int j = 0; j < 4; ++j)
        acc[i][j] =
            __builtin_amdgcn_mfma_f32_16x16x32_f16(af[i], bf[j], acc[i][j], 0, 0, 0);
    cur ^= 1;
  }

  // C/D frag: lane holds D[row=quad*4+r][col=lm] per 16x16 tile
#pragma unroll
  for (int i = 0; i < 4; ++i)
#pragma unroll
    for (int r = 0; r < 4; ++r) {
      size_t row = (size_t)(m0 + wm + i * 16 + quad * 4 + r) * N;
#pragma unroll
      for (int j = 0; j < 4; ++j)
        store1(&C[row + n0 + wn + j * 16 + lm], acc[i][j][r]);
    }
}

// ---------- RoPE in place on fp16 [B*T, H, 64]; position = row % T ----------
// (used for K only; Q-rope is fused into attn_mfma's register load)
__global__ void rope_kernel(__half* __restrict__ X, int T, int H, int total_pairs) {
  int idx = blockIdx.x * blockDim.x + threadIdx.x;
  if (idx >= total_pairs) return;
  int i   = idx & 31;
  int h   = (idx >> 5) % H;
  int row = idx / (32 * H);
  int tpos = row % T;
  __half* p = X + ((size_t)row * H + h) * DK;
  // 10000^(-i/32) = exp2(-i * log2(10000)/32)
  float inv = exp2f((float)i * -0.41524101186091403f);
  float ang = (float)tpos * inv;
  float c, s;
  sincosf(ang, &s, &c);
  float x1 = __half2float(p[i]), x2 = __half2float(p[i + 32]);
  p[i]      = __float2half(x1 * c - x2 * s);
  p[i + 32] = __float2half(x2 * c + x1 * s);
}

// ---------- MFMA flash attention, 32x32 frags, swapped QK^T ----------
// Block = 4 waves (256 thr) = 128 q rows; wave w owns rows [qt*128+w*32, +32).
// mfma_f32_32x32x16_f16 layouts:
//   A-frag: lane holds A[m=lane&31][k=8*(lane>>5)+j], j=0..7
//   B-frag: lane holds B[k=8*(lane>>5)+j][n=lane&31]
//   C/D   : lane holds D[row=(reg&3)+8*(reg>>2)+4*(lane>>5)][col=lane&31]
// Swapped QK^T: st = mfma(A=K, B=Q) = S^T[key][q]; lane's 16 regs hold the
// scores of q-column lq for 16 of the tile's 32 keys (other half at lane+32).
// Per-32-key-tile processing (ONE f32x16 st) + scalar column-space l_run
// keep the live set ~120 regs. __launch_bounds__(256,3): budget ~168 regs
// -> NO SPILL (R8/R9 lesson: (256,4)'s 128-budget spills ~8MB scratch),
// 3 blocks/CU = 12 waves (vs 8 at (256,2)) on a VALU-issue-bound kernel.
// P stays in registers: cvt_pkrtz pack -> one half-swap per dword pair into
// PV A-frags. Defer-rescale (T13, THR=8 -> P<=256, f16-safe).
// Q-RoPE fused (+0.125*log2e scale folded into Q): softmax fully base-2.
// O aliases Q safely: wave reads only its own q rows first, writes them last.
#define AP 72  // LDS pitch (f16): 144B rows -> b128-aligned, balanced banks
#define C2 0.18033688011112042f  // 0.125 * log2(e)
#define RLOG2 -0.41524101186091403f  // -log2(10000)/32
__global__ __launch_bounds__(256, 3) void attn_mfma(const __half* Q,
                                                    const __half* __restrict__ K,
                                                    const __half* __restrict__ V,
                                                    __half* O) {
  __shared__ _Float16 Ks[64 * AP];        // [key][d]
  __shared__ _Float16 Vt[64 * AP];        // [d][key]
  const int t = threadIdx.x;
  const int w = t >> 6, l = t & 63;
  const int lq = l & 31, hi = l >> 5;
  const int qt = blockIdx.x, h = blockIdx.y, b = blockIdx.z;
  const int kvh = h >> 2;

  // Q B-frags (registers, whole kernel): aq[kc] = Q[qrow][kc*16+8*hi+j]
  const __half* qbase =
      Q + (((size_t)b * TQ + qt * 128 + w * 32 + lq) * NH + h) * DK;
  f16x8 aq[4];
#pragma unroll
  for (int kc = 0; kc < 4; ++kc)
    aq[kc] = *(const f16x8*)(qbase + kc * 16 + hi * 8);

  // fused RoPE on Q (in-register) + fold C2 scale: pair (d, d+32) =
  // (aq[kc][j], aq[kc+2][j]); after this, S^T is directly base-2 scores.
  {
    const float tpos = (float)(qt * 128 + w * 32 + lq);
#pragma unroll
    for (int kc = 0; kc < 2; ++kc)
#pragma unroll
      for (int j = 0; j < 8; ++j) {
        int d = kc * 16 + hi * 8 + j;
        float inv = exp2f((float)d * RLOG2);
        float ang = tpos * inv;
        float c, s;
        sincosf(ang, &s, &c);
        float x1 = (float)aq[kc][j], x2 = (float)aq[kc + 2][j];
        aq[kc][j]     = (_Float16)((x1 * c - x2 * s) * C2);
        aq[kc + 2][j] = (_Float16)((x2 * c + x1 * s) * C2);
      }
  }

  // staging: 2 x 16B units per thread for K and V each (64x64 f16 tiles)
  const int skey = t >> 3, sdseg = t & 7;          // K [key][d], +32 keys r=1
  const int vkey = t & 63, vdb0 = (t >> 6) * 8;    // V -> Vt [d][key], +32 d r=1
  const __half* kp0 =
      K + (((size_t)b * TKV + skey) * NKV + kvh) * DK + sdseg * 8;
  const __half* kp1 = kp0 + (size_t)32 * NKV * DK;
  const __half* vp0 =
      V + (((size_t)b * TKV + vkey) * NKV + kvh) * DK + vdb0;
  const __half* vp1 = vp0 + 32;
  const size_t kstep = (size_t)64 * NKV * DK;  // 64 keys forward

  f16x8 kpre0 = *(const f16x8*)kp0, kpre1 = *(const f16x8*)kp1;
  f16x8 vpre0 = *(const f16x8*)vp0, vpre1 = *(const f16x8*)vp1;

  f32x16 o_acc[2];
#pragma unroll
  for (int i = 0; i < 16; ++i) { o_acc[0][i] = 0.f; o_acc[1][i] = 0.f; }
  float m_run = -1e30f, l_run = 0.0f;  // column space (q = lq)

  for (int ck = 0; ck < TKV / 64; ++ck) {
    __syncthreads();  // prior chunk's Ks/Vt reads done
    *(f16x8*)&Ks[skey * AP + sdseg * 8] = kpre0;
    *(f16x8*)&Ks[(skey + 32) * AP + sdseg * 8] = kpre1;
#pragma unroll
    for (int j = 0; j < 8; ++j) {
      Vt[(vdb0 + j) * AP + vkey] = vpre0[j];
      Vt[(vdb0 + 32 + j) * AP + vkey] = vpre1[j];
    }
    __syncthreads();
    // T14: issue next chunk's loads now; latency hides under compute below
    if (ck + 1 < TKV / 64) {
      size_t off = (size_t)(ck + 1) * kstep;
      kpre0 = *(const f16x8*)(kp0 + off);
      kpre1 = *(const f16x8*)(kp1 + off);
      vpre0 = *(const f16x8*)(vp0 + off);
      vpre1 = *(const f16x8*)(vp1 + off);
    }

#pragma unroll
    for (int tile = 0; tile < 2; ++tile) {
      // S^T = K Q^T for keys [tile*32, +32) x 32 q-cols
      f32x16 st;
#pragma unroll
      for (int i = 0; i < 16; ++i) st[i] = 0.f;
      __builtin_amdgcn_s_setprio(1);
#pragma unroll
      for (int kc = 0; kc < 4; ++kc) {
        f16x8 ak =
            *(const f16x8*)&Ks[(tile * 32 + lq) * AP + kc * 16 + hi * 8];
        st = __builtin_amdgcn_mfma_f32_32x32x16_f16(ak, aq[kc], st, 0, 0, 0);
      }
      __builtin_amdgcn_s_setprio(0);

      // column max (q = lq): in-lane over 16 regs, then swap halves
      float vmax = st[0];
#pragma unroll
      for (int i = 1; i < 16; ++i) vmax = fmaxf(vmax, st[i]);
      vmax = fmaxf(vmax, __shfl_xor(vmax, 32));

      // T13 defer-rescale: only pay when max grew past THR
      if (!__all(vmax - m_run <= 8.0f)) {
        float m_new = fmaxf(m_run, vmax);
        float alpha = exp2f(m_run - m_new);  // column space
        m_run = m_new;
        l_run *= alpha;
#pragma unroll
        for (int reg = 0; reg < 16; ++reg) {
          int row = (reg & 3) + 8 * (reg >> 2) + 4 * hi;
          float ar = __shfl(alpha, row);     // alpha for q-row of this reg
          o_acc[0][reg] *= ar;
          o_acc[1][reg] *= ar;
        }
      }

      // P = 2^(st - m): pack to f16 pairs; l_run += column sum
      unsigned q16u[8];
      float psum = 0.0f;
#pragma unroll
      for (int rr = 0; rr < 8; ++rr) {
        float p0 = exp2f(st[2 * rr] - m_run);
        float p1 = exp2f(st[2 * rr + 1] - m_run);
        psum += p0 + p1;
        q16u[rr] = pack2h(p0, p1);
      }
      psum += __shfl_xor(psum, 32);  // other half's 16 keys
      l_run += psum;

      // Redistribute P^T (column space) -> PV A-frags (row space); O += P V
      __builtin_amdgcn_s_setprio(1);
#pragma unroll
      for (int kb = 0; kb < 2; ++kb) {
        const int base = kb * 4;
        union { unsigned u[4]; f16x8 v; } ap;
#pragma unroll
        for (int c = 0; c < 2; ++c) {
          unsigned R0 = q16u[base + c];       // reg wanted by hi_t=0
          unsigned R1 = q16u[base + 2 + c];   // reg wanted by hi_t=1
          unsigned Z = hi ? R0 : R1;          // what my partner wants
          unsigned Xp = __shfl_xor(Z, 32);    // partner's Z (what I want)
          ap.u[c]     = hi ? Xp : R0;         // from hi=0 half
          ap.u[c + 2] = hi ? R1 : Xp;         // from hi=1 half
        }
#pragma unroll
        for (int nt = 0; nt < 2; ++nt) {
          f16x8 bv = *(const f16x8*)&Vt[(nt * 32 + lq) * AP + tile * 32 +
                                        kb * 16 + hi * 8];
          o_acc[nt] =
              __builtin_amdgcn_mfma_f32_32x32x16_f16(ap.v, bv, o_acc[nt], 0, 0, 0);
        }
      }
      __builtin_amdgcn_s_setprio(0);
    }
  }

  // epilogue: row = (reg&3)+8*(reg>>2)+4*hi, cols d = nt*32 + lq;
  // l_run is column-space -> fetch per-row value by lane shuffle.
#pragma unroll
  for (int reg = 0; reg < 16; ++reg) {
    int row = (reg & 3) + 8 * (reg >> 2) + 4 * hi;
    float inv = 1.0f / __shfl(l_run, row);
    size_t orow =
        (((size_t)b * TQ + qt * 128 + w * 32 + row) * NH + h) * DK;
    O[orow + lq]      = __float2half(o_acc[0][reg] * inv);
    O[orow + 32 + lq] = __float2half(o_acc[1][reg] * inv);
  }
}

extern "C" void kernel_launch(void* const* d_in, const int* in_sizes, int n_in,
                              void* d_out, int out_size, void* d_ws, size_t ws_size,
                              hipStream_t stream) {
  // ---- Input mapping via in_sizes pattern (dict vs sorted-key order) ----
  int iq, ikv, iwq, iwk, iwv, iwo;
  bool ok = true;
  if (n_in >= 8 && in_sizes[0] == 8388608 && in_sizes[1] == 8388608) {
    iq = 0; ikv = 1; iwq = 4; iwk = 5; iwv = 6; iwo = 7;          // dict order
  } else if (n_in >= 8 && in_sizes[0] == 8388608 && in_sizes[1] == 8192) {
    ikv = 0; iq = 2; iwk = 4; iwo = 5; iwq = 6; iwv = 7;          // sorted keys
  } else if (n_in == 6 && in_sizes[2] == 1048576) {
    iq = 0; ikv = 1; iwq = 2; iwk = 3; iwv = 4; iwo = 5;          // dict, no masks
  } else if (n_in == 6 && in_sizes[2] == 262144) {
    ikv = 0; iq = 1; iwk = 2; iwo = 3; iwq = 4; iwv = 5;          // sorted, no masks
  } else {
    ok = false; iq = ikv = iwq = iwk = iwv = iwo = 0;
  }

  const size_t nQ  = (size_t)B_ * TQ * DM;
  const size_t nKV = (size_t)B_ * TKV * NKV * DK;
  const size_t need = (nQ + 2 * nKV) * sizeof(__half);  // 24 MB
  if (!ok || ws_size < need) {
    zero_out_kernel<<<(out_size + 255) / 256, 256, 0, stream>>>((float*)d_out,
                                                                out_size);
    return;
  }

  const float* query     = (const float*)d_in[iq];
  const float* key_value = (const float*)d_in[ikv];
  const float* w_q   = (const float*)d_in[iwq];
  const float* w_k   = (const float*)d_in[iwk];
  const float* w_v   = (const float*)d_in[iwv];
  const float* w_out = (const float*)d_in[iwo];
  float* out = (float*)d_out;

  __half* Qh = (__half*)d_ws;
  __half* Kh = Qh + nQ;
  __half* Vh = Kh + nKV;

  dim3 blk(256);
  // Q projection: M=8192, N=1024, K=1024 (Q-rope fused into attn)
  gemm_bt_mfma<<<dim3(DM / 128, B_ * TQ / 128, 1), blk, 0, stream>>>(
      query, w_q, w_q, Qh, Qh, B_ * TQ, DM, DM);
  // K and V projections fused in one launch (z selects weight/output):
  // M=8192, N=256, K=1024 each -> 2*2*64 = 256 blocks
  gemm_bt_mfma<<<dim3(NKV * DK / 128, B_ * TKV / 128, 2), blk, 0, stream>>>(
      key_value, w_k, w_v, Kh, Vh, B_ * TKV, NKV * DK, DM);
  int pk = B_ * TKV * NKV * 32;
  rope_kernel<<<(pk + 255) / 256, blk, 0, stream>>>(Kh, TKV, NKV, pk);
  // MFMA flash attention (32x32 frags, P-in-register, fused Q-rope)
  attn_mfma<<<dim3(TQ / 128, NH, B_), dim3(256), 0, stream>>>(Qh, Kh, Vh, Qh);
  // Output projection: M=8192, N=1024, K=1024, fp32 out (f16 A input)
  gemm_bt_mfma<<<dim3(DM / 128, B_ * TQ / 128, 1), blk, 0, stream>>>(
      Qh, w_out, w_out, out, out, B_ * TQ, DM, DM);
}

// Round 11
// 363.845 us; speedup vs baseline: 1.2785x; 1.0659x over previous
//
#include <hip/hip_runtime.h>
#include <hip/hip_bf16.h>
#include <hip/hip_fp16.h>

// Problem constants (CrossAttention_17076789969260)
// Inputs: fp32 buffers (bf16-rounded values). Output: fp32 buffer.
#define B_    4
#define TQ    2048
#define TKV   2048
#define DM    1024
#define NH    16
#define NKV   4
#define DK    64

typedef _Float16 f16x8 __attribute__((ext_vector_type(8)));
typedef _Float16 f16x4 __attribute__((ext_vector_type(4)));
typedef float    f32x4 __attribute__((ext_vector_type(4)));
typedef float    f32x16 __attribute__((ext_vector_type(16)));

__device__ __forceinline__ void store1(float* p, float v) { *p = v; }
__device__ __forceinline__ void store1(__half* p, float v) {
  union { __half h; unsigned short u; } c; c.h = __float2half(v);
  *(unsigned short*)p = c.u;
}

// 4-element fragment loaders for GEMM staging (result: f16x4).
__device__ __forceinline__ f16x4 load4h(const float* p) {
  float4 v = *(const float4*)p;
  f16x4 r;
  r[0] = (_Float16)v.x; r[1] = (_Float16)v.y;
  r[2] = (_Float16)v.z; r[3] = (_Float16)v.w;
  return r;
}
__device__ __forceinline__ f16x4 load4h(const __half* p) {
  return *(const f16x4*)p;  // already f16
}

// pack two fp32 -> 2 x f16 dword (RTZ), type-safe across ROCm versions
__device__ __forceinline__ unsigned pack2h(float a, float b) {
  auto pk = __builtin_amdgcn_cvt_pkrtz(a, b);
  unsigned u;
  __builtin_memcpy(&u, &pk, 4);
  return u;
}

__global__ void zero_out_kernel(float* out, int n) {
  int i = blockIdx.x * blockDim.x + threadIdx.x;
  if (i < n) out[i] = 0.0f;
}

// ---------- MFMA projection GEMM: C[M,N] = A[M,K] @ W[N,K]^T ----------
// BM=64 x BN=128 tile, BK=32, 4 waves 2x2 (wave = 32x64, 8 mfma/K-step,
// acc = 32 VGPR). Rationale (R11): the 128x128 tile ran at 2 blocks/CU
// (Q-proj grid 512, KV-proj 256 -> 1/CU) and ~180 TF, latency-bound with
// MfmaUtil~0-20; 64x128 doubles the grid (Q: 1024 blocks) and LDS 30.7KB +
// ~70 VGPR give ~5 blocks/CU resident -> 2.5x latency hiding.
// Double-buffered LDS + register prefetch per K-step (unchanged pattern):
// {write regs->LDS[cur]; ONE barrier; issue k+1 loads; ds_read frags; MFMA}.
// fp32->f16 conversion fused into staging (inputs bf16-rounded -> exact).
// FUSED 1D-grid decode: bid<1024 -> Q-proj tile (A0,W0,C0, N0, bx<8);
// next 256 -> K-proj (A1,W1,C1, Nkv, bx<2); next 256 -> V-proj (A1,W2,C2).
// The out-proj launch uses grid=1024 (z=0 path only, AT=__half, CT=float).
#define GAP 40
#define BM 64
#define BN 128
template <typename AT, typename CT>
__global__ __launch_bounds__(256) void gemm_proj(
    const AT* __restrict__ A0, const AT* __restrict__ A1,
    const float* __restrict__ W0, const float* __restrict__ W1,
    const float* __restrict__ W2,
    CT* __restrict__ C0, CT* __restrict__ C1, CT* __restrict__ C2,
    int N0, int Nkv, int K) {
  const int bid = blockIdx.x;
  const AT* __restrict__ A;
  const float* __restrict__ W;
  CT* __restrict__ C;
  int N, bx, by;
  if (bid < 1024) {
    A = A0; W = W0; C = C0; N = N0;
    bx = bid & 7; by = bid >> 3;
  } else {
    int r = bid - 1024;
    A = A1; N = Nkv;
    if (r < 256) { W = W1; C = C1; } else { W = W2; C = C2; r -= 256; }
    bx = r & 1; by = r >> 1;
  }

  __shared__ _Float16 As[2 * BM * GAP];
  __shared__ _Float16 Ws[2 * BN * GAP];

  const int t = threadIdx.x;
  const int w = t >> 6, l = t & 63;
  const int lm = l & 15, quad = l >> 4;
  const int wm = (w >> 1) * 32, wn = (w & 1) * 64;
  const int m0 = by * BM, n0 = bx * BN;

  // staging: 8 lanes per 32-elem row; 32 rows/pass; A 2 passes, W 4 passes
  const int srow = t >> 3;        // 0..31
  const int scol = (t & 7) * 4;   // 0,4,..,28

  f32x4 acc[2][4] = {};
  f16x4 av[2], wv[4];
  // prologue: K-step 0 into regs
#pragma unroll
  for (int p = 0; p < 2; ++p)
    av[p] = load4h(&A[(size_t)(m0 + srow + p * 32) * K + scol]);
#pragma unroll
  for (int p = 0; p < 4; ++p)
    wv[p] = load4h(&W[(size_t)(n0 + srow + p * 32) * K + scol]);

  int cur = 0;
  for (int k0 = 0; k0 < K; k0 += 32) {
    _Float16* as = &As[cur * BM * GAP];
    _Float16* ws = &Ws[cur * BN * GAP];
#pragma unroll
    for (int p = 0; p < 2; ++p)
      *(f16x4*)&as[(srow + p * 32) * GAP + scol] = av[p];
#pragma unroll
    for (int p = 0; p < 4; ++p)
      *(f16x4*)&ws[(srow + p * 32) * GAP + scol] = wv[p];
    __syncthreads();
    // issue next K-step's loads; latency hides under frag reads + MFMA
    if (k0 + 32 < K) {
#pragma unroll
      for (int p = 0; p < 2; ++p)
        av[p] = load4h(&A[(size_t)(m0 + srow + p * 32) * K + k0 + 32 + scol]);
#pragma unroll
      for (int p = 0; p < 4; ++p)
        wv[p] = load4h(&W[(size_t)(n0 + srow + p * 32) * K + k0 + 32 + scol]);
    }

    f16x8 af[2], bf[4];
#pragma unroll
    for (int i = 0; i < 2; ++i)
      af[i] = *(const f16x8*)&as[(wm + i * 16 + lm) * GAP + quad * 8];
#pragma unroll
    for (int j = 0; j < 4; ++j)
      bf[j] = *(const f16x8*)&ws[(wn + j * 16 + lm) * GAP + quad * 8];
#pragma unroll
    for (int i = 0; i < 2; ++i)
#pragma unroll
      for (int j = 0; j < 4; ++j)
        acc[i][j] =
            __builtin_amdgcn_mfma_f32_16x16x32_f16(af[i], bf[j], acc[i][j], 0, 0, 0);
    cur ^= 1;
  }

  // C/D frag: lane holds D[row=quad*4+r][col=lm] per 16x16 tile
#pragma unroll
  for (int i = 0; i < 2; ++i)
#pragma unroll
    for (int r = 0; r < 4; ++r) {
      size_t row = (size_t)(m0 + wm + i * 16 + quad * 4 + r) * N;
#pragma unroll
      for (int j = 0; j < 4; ++j)
        store1(&C[row + n0 + wn + j * 16 + lm], acc[i][j][r]);
    }
}

// ---------- RoPE in place on fp16 [B*T, H, 64]; position = row % T ----------
// (used for K only; Q-rope is fused into attn_mfma's register load)
__global__ void rope_kernel(__half* __restrict__ X, int T, int H, int total_pairs) {
  int idx = blockIdx.x * blockDim.x + threadIdx.x;
  if (idx >= total_pairs) return;
  int i   = idx & 31;
  int h   = (idx >> 5) % H;
  int row = idx / (32 * H);
  int tpos = row % T;
  __half* p = X + ((size_t)row * H + h) * DK;
  // 10000^(-i/32) = exp2(-i * log2(10000)/32)
  float inv = exp2f((float)i * -0.41524101186091403f);
  float ang = (float)tpos * inv;
  float c, s;
  sincosf(ang, &s, &c);
  float x1 = __half2float(p[i]), x2 = __half2float(p[i + 32]);
  p[i]      = __float2half(x1 * c - x2 * s);
  p[i + 32] = __float2half(x2 * c + x1 * s);
}

// ---------- MFMA flash attention, 32x32 frags, swapped QK^T ----------
// (R10-exact; attention is VALU-issue-bound at ~144-150us across occupancy
// settings -- left untouched this round to isolate the GEMM change.)
#define AP 72  // LDS pitch (f16): 144B rows -> b128-aligned, balanced banks
#define C2 0.18033688011112042f  // 0.125 * log2(e)
#define RLOG2 -0.41524101186091403f  // -log2(10000)/32
__global__ __launch_bounds__(256, 3) void attn_mfma(const __half* Q,
                                                    const __half* __restrict__ K,
                                                    const __half* __restrict__ V,
                                                    __half* O) {
  __shared__ _Float16 Ks[64 * AP];        // [key][d]
  __shared__ _Float16 Vt[64 * AP];        // [d][key]
  const int t = threadIdx.x;
  const int w = t >> 6, l = t & 63;
  const int lq = l & 31, hi = l >> 5;
  const int qt = blockIdx.x, h = blockIdx.y, b = blockIdx.z;
  const int kvh = h >> 2;

  // Q B-frags (registers, whole kernel): aq[kc] = Q[qrow][kc*16+8*hi+j]
  const __half* qbase =
      Q + (((size_t)b * TQ + qt * 128 + w * 32 + lq) * NH + h) * DK;
  f16x8 aq[4];
#pragma unroll
  for (int kc = 0; kc < 4; ++kc)
    aq[kc] = *(const f16x8*)(qbase + kc * 16 + hi * 8);

  // fused RoPE on Q (in-register) + fold C2 scale: pair (d, d+32) =
  // (aq[kc][j], aq[kc+2][j]); after this, S^T is directly base-2 scores.
  {
    const float tpos = (float)(qt * 128 + w * 32 + lq);
#pragma unroll
    for (int kc = 0; kc < 2; ++kc)
#pragma unroll
      for (int j = 0; j < 8; ++j) {
        int d = kc * 16 + hi * 8 + j;
        float inv = exp2f((float)d * RLOG2);
        float ang = tpos * inv;
        float c, s;
        sincosf(ang, &s, &c);
        float x1 = (float)aq[kc][j], x2 = (float)aq[kc + 2][j];
        aq[kc][j]     = (_Float16)((x1 * c - x2 * s) * C2);
        aq[kc + 2][j] = (_Float16)((x2 * c + x1 * s) * C2);
      }
  }

  // staging: 2 x 16B units per thread for K and V each (64x64 f16 tiles)
  const int skey = t >> 3, sdseg = t & 7;          // K [key][d], +32 keys r=1
  const int vkey = t & 63, vdb0 = (t >> 6) * 8;    // V -> Vt [d][key], +32 d r=1
  const __half* kp0 =
      K + (((size_t)b * TKV + skey) * NKV + kvh) * DK + sdseg * 8;
  const __half* kp1 = kp0 + (size_t)32 * NKV * DK;
  const __half* vp0 =
      V + (((size_t)b * TKV + vkey) * NKV + kvh) * DK + vdb0;
  const __half* vp1 = vp0 + 32;
  const size_t kstep = (size_t)64 * NKV * DK;  // 64 keys forward

  f16x8 kpre0 = *(const f16x8*)kp0, kpre1 = *(const f16x8*)kp1;
  f16x8 vpre0 = *(const f16x8*)vp0, vpre1 = *(const f16x8*)vp1;

  f32x16 o_acc[2];
#pragma unroll
  for (int i = 0; i < 16; ++i) { o_acc[0][i] = 0.f; o_acc[1][i] = 0.f; }
  float m_run = -1e30f, l_run = 0.0f;  // column space (q = lq)

  for (int ck = 0; ck < TKV / 64; ++ck) {
    __syncthreads();  // prior chunk's Ks/Vt reads done
    *(f16x8*)&Ks[skey * AP + sdseg * 8] = kpre0;
    *(f16x8*)&Ks[(skey + 32) * AP + sdseg * 8] = kpre1;
#pragma unroll
    for (int j = 0; j < 8; ++j) {
      Vt[(vdb0 + j) * AP + vkey] = vpre0[j];
      Vt[(vdb0 + 32 + j) * AP + vkey] = vpre1[j];
    }
    __syncthreads();
    // T14: issue next chunk's loads now; latency hides under compute below
    if (ck + 1 < TKV / 64) {
      size_t off = (size_t)(ck + 1) * kstep;
      kpre0 = *(const f16x8*)(kp0 + off);
      kpre1 = *(const f16x8*)(kp1 + off);
      vpre0 = *(const f16x8*)(vp0 + off);
      vpre1 = *(const f16x8*)(vp1 + off);
    }

#pragma unroll
    for (int tile = 0; tile < 2; ++tile) {
      // S^T = K Q^T for keys [tile*32, +32) x 32 q-cols
      f32x16 st;
#pragma unroll
      for (int i = 0; i < 16; ++i) st[i] = 0.f;
      __builtin_amdgcn_s_setprio(1);
#pragma unroll
      for (int kc = 0; kc < 4; ++kc) {
        f16x8 ak =
            *(const f16x8*)&Ks[(tile * 32 + lq) * AP + kc * 16 + hi * 8];
        st = __builtin_amdgcn_mfma_f32_32x32x16_f16(ak, aq[kc], st, 0, 0, 0);
      }
      __builtin_amdgcn_s_setprio(0);

      // column max (q = lq): in-lane over 16 regs, then swap halves
      float vmax = st[0];
#pragma unroll
      for (int i = 1; i < 16; ++i) vmax = fmaxf(vmax, st[i]);
      vmax = fmaxf(vmax, __shfl_xor(vmax, 32));

      // T13 defer-rescale: only pay when max grew past THR
      if (!__all(vmax - m_run <= 8.0f)) {
        float m_new = fmaxf(m_run, vmax);
        float alpha = exp2f(m_run - m_new);  // column space
        m_run = m_new;
        l_run *= alpha;
#pragma unroll
        for (int reg = 0; reg < 16; ++reg) {
          int row = (reg & 3) + 8 * (reg >> 2) + 4 * hi;
          float ar = __shfl(alpha, row);     // alpha for q-row of this reg
          o_acc[0][reg] *= ar;
          o_acc[1][reg] *= ar;
        }
      }

      // P = 2^(st - m): pack to f16 pairs; l_run += column sum
      unsigned q16u[8];
      float psum = 0.0f;
#pragma unroll
      for (int rr = 0; rr < 8; ++rr) {
        float p0 = exp2f(st[2 * rr] - m_run);
        float p1 = exp2f(st[2 * rr + 1] - m_run);
        psum += p0 + p1;
        q16u[rr] = pack2h(p0, p1);
      }
      psum += __shfl_xor(psum, 32);  // other half's 16 keys
      l_run += psum;

      // Redistribute P^T (column space) -> PV A-frags (row space); O += P V
      __builtin_amdgcn_s_setprio(1);
#pragma unroll
      for (int kb = 0; kb < 2; ++kb) {
        const int base = kb * 4;
        union { unsigned u[4]; f16x8 v; } ap;
#pragma unroll
        for (int c = 0; c < 2; ++c) {
          unsigned R0 = q16u[base + c];       // reg wanted by hi_t=0
          unsigned R1 = q16u[base + 2 + c];   // reg wanted by hi_t=1
          unsigned Z = hi ? R0 : R1;          // what my partner wants
          unsigned Xp = __shfl_xor(Z, 32);    // partner's Z (what I want)
          ap.u[c]     = hi ? Xp : R0;         // from hi=0 half
          ap.u[c + 2] = hi ? R1 : Xp;         // from hi=1 half
        }
#pragma unroll
        for (int nt = 0; nt < 2; ++nt) {
          f16x8 bv = *(const f16x8*)&Vt[(nt * 32 + lq) * AP + tile * 32 +
                                        kb * 16 + hi * 8];
          o_acc[nt] =
              __builtin_amdgcn_mfma_f32_32x32x16_f16(ap.v, bv, o_acc[nt], 0, 0, 0);
        }
      }
      __builtin_amdgcn_s_setprio(0);
    }
  }

  // epilogue: row = (reg&3)+8*(reg>>2)+4*hi, cols d = nt*32 + lq;
  // l_run is column-space -> fetch per-row value by lane shuffle.
#pragma unroll
  for (int reg = 0; reg < 16; ++reg) {
    int row = (reg & 3) + 8 * (reg >> 2) + 4 * hi;
    float inv = 1.0f / __shfl(l_run, row);
    size_t orow =
        (((size_t)b * TQ + qt * 128 + w * 32 + row) * NH + h) * DK;
    O[orow + lq]      = __float2half(o_acc[0][reg] * inv);
    O[orow + 32 + lq] = __float2half(o_acc[1][reg] * inv);
  }
}

extern "C" void kernel_launch(void* const* d_in, const int* in_sizes, int n_in,
                              void* d_out, int out_size, void* d_ws, size_t ws_size,
                              hipStream_t stream) {
  // ---- Input mapping via in_sizes pattern (dict vs sorted-key order) ----
  int iq, ikv, iwq, iwk, iwv, iwo;
  bool ok = true;
  if (n_in >= 8 && in_sizes[0] == 8388608 && in_sizes[1] == 8388608) {
    iq = 0; ikv = 1; iwq = 4; iwk = 5; iwv = 6; iwo = 7;          // dict order
  } else if (n_in >= 8 && in_sizes[0] == 8388608 && in_sizes[1] == 8192) {
    ikv = 0; iq = 2; iwk = 4; iwo = 5; iwq = 6; iwv = 7;          // sorted keys
  } else if (n_in == 6 && in_sizes[2] == 1048576) {
    iq = 0; ikv = 1; iwq = 2; iwk = 3; iwv = 4; iwo = 5;          // dict, no masks
  } else if (n_in == 6 && in_sizes[2] == 262144) {
    ikv = 0; iq = 1; iwk = 2; iwo = 3; iwq = 4; iwv = 5;          // sorted, no masks
  } else {
    ok = false; iq = ikv = iwq = iwk = iwv = iwo = 0;
  }

  const size_t nQ  = (size_t)B_ * TQ * DM;
  const size_t nKV = (size_t)B_ * TKV * NKV * DK;
  const size_t need = (nQ + 2 * nKV) * sizeof(__half);  // 24 MB
  if (!ok || ws_size < need) {
    zero_out_kernel<<<(out_size + 255) / 256, 256, 0, stream>>>((float*)d_out,
                                                                out_size);
    return;
  }

  const float* query     = (const float*)d_in[iq];
  const float* key_value = (const float*)d_in[ikv];
  const float* w_q   = (const float*)d_in[iwq];
  const float* w_k   = (const float*)d_in[iwk];
  const float* w_v   = (const float*)d_in[iwv];
  const float* w_out = (const float*)d_in[iwo];
  float* out = (float*)d_out;

  __half* Qh = (__half*)d_ws;
  __half* Kh = Qh + nQ;
  __half* Vh = Kh + nKV;

  dim3 blk(256);
  // Fused Q/K/V projections, one 1536-block launch:
  // bid<1024: Q-proj (M=8192,N=1024); +256: K-proj; +256: V-proj (N=256).
  gemm_proj<<<dim3(1536), blk, 0, stream>>>(query, key_value, w_q, w_k, w_v,
                                            Qh, Kh, Vh, DM, NKV * DK, DM);
  int pk = B_ * TKV * NKV * 32;
  rope_kernel<<<(pk + 255) / 256, blk, 0, stream>>>(Kh, TKV, NKV, pk);
  // MFMA flash attention (32x32 frags, P-in-register, fused Q-rope)
  attn_mfma<<<dim3(TQ / 128, NH, B_), dim3(256), 0, stream>>>(Qh, Kh, Vh, Qh);
  // Output projection: M=8192, N=1024, K=1024, fp32 out (f16 A input);
  // grid 1024 -> z=0 path only.
  gemm_proj<<<dim3(1024), blk, 0, stream>>>(Qh, Qh, w_out, w_out, w_out,
                                            out, out, out, DM, DM, DM);
}

// Round 12
// 359.289 us; speedup vs baseline: 1.2947x; 1.0127x over previous
//
#include <hip/hip_runtime.h>
#include <hip/hip_bf16.h>
#include <hip/hip_fp16.h>

// Problem constants (CrossAttention_17076789969260)
// Inputs: fp32 buffers (bf16-rounded values). Output: fp32 buffer.
#define B_    4
#define TQ    2048
#define TKV   2048
#define DM    1024
#define NH    16
#define NKV   4
#define DK    64

typedef _Float16 f16x8 __attribute__((ext_vector_type(8)));
typedef _Float16 f16x4 __attribute__((ext_vector_type(4)));
typedef float    f32x4 __attribute__((ext_vector_type(4)));
typedef float    f32x16 __attribute__((ext_vector_type(16)));

__device__ __forceinline__ void store1(float* p, float v) { *p = v; }
__device__ __forceinline__ void store1(__half* p, float v) {
  union { __half h; unsigned short u; } c; c.h = __float2half(v);
  *(unsigned short*)p = c.u;
}

// pack two fp32 -> 2 x f16 dword (RTZ; exact on bf16-rounded inputs)
__device__ __forceinline__ unsigned pack2h(float a, float b) {
  auto pk = __builtin_amdgcn_cvt_pkrtz(a, b);
  unsigned u;
  __builtin_memcpy(&u, &pk, 4);
  return u;
}

// 4-element fragment loaders for GEMM staging (result: f16x4).
// fp32 path: packed cvt (2 x v_cvt_pkrtz instead of 4 scalar casts) --
// R12 isolated test of the staging-VALU theory (R8 bundled this with
// two regressions; attribution was impossible).
__device__ __forceinline__ f16x4 load4h(const float* p) {
  float4 v = *(const float4*)p;
  union { unsigned u[2]; f16x4 h; } c;
  c.u[0] = pack2h(v.x, v.y);
  c.u[1] = pack2h(v.z, v.w);
  return c.h;
}
__device__ __forceinline__ f16x4 load4h(const __half* p) {
  return *(const f16x4*)p;  // already f16
}

// 3-input max (clang fuses nested fmaxf to v_max3_f32)
__device__ __forceinline__ float fmax3(float a, float b, float c) {
  return fmaxf(fmaxf(a, b), c);
}

__global__ void zero_out_kernel(float* out, int n) {
  int i = blockIdx.x * blockDim.x + threadIdx.x;
  if (i < n) out[i] = 0.0f;
}

// ---------- MFMA projection GEMM: C[M,N] = A[M,K] @ W[N,K]^T ----------
// BM=64 x BN=128 tile, BK=32, 4 waves 2x2 (wave = 32x64, 8 mfma/K-step,
// acc = 32 VGPR). 64x128 tile -> Q-proj grid 1024, ~5 blocks/CU resident.
// Double-buffered LDS + register prefetch per K-step:
// {write regs->LDS[cur]; ONE barrier; issue k+1 loads; ds_read frags; MFMA}.
// fp32->f16 conversion fused into staging (packed cvt, see load4h).
// FUSED 1D-grid decode: bid<1024 -> Q-proj tile (A0,W0,C0, N0, bx<8);
// next 256 -> K-proj (A1,W1,C1, Nkv, bx<2); next 256 -> V-proj (A1,W2,C2).
// The out-proj launch uses grid=1024 (z=0 path only, AT=__half, CT=float).
#define GAP 40
#define BM 64
#define BN 128
template <typename AT, typename CT>
__global__ __launch_bounds__(256) void gemm_proj(
    const AT* __restrict__ A0, const AT* __restrict__ A1,
    const float* __restrict__ W0, const float* __restrict__ W1,
    const float* __restrict__ W2,
    CT* __restrict__ C0, CT* __restrict__ C1, CT* __restrict__ C2,
    int N0, int Nkv, int K) {
  const int bid = blockIdx.x;
  const AT* __restrict__ A;
  const float* __restrict__ W;
  CT* __restrict__ C;
  int N, bx, by;
  if (bid < 1024) {
    A = A0; W = W0; C = C0; N = N0;
    bx = bid & 7; by = bid >> 3;
  } else {
    int r = bid - 1024;
    A = A1; N = Nkv;
    if (r < 256) { W = W1; C = C1; } else { W = W2; C = C2; r -= 256; }
    bx = r & 1; by = r >> 1;
  }

  __shared__ _Float16 As[2 * BM * GAP];
  __shared__ _Float16 Ws[2 * BN * GAP];

  const int t = threadIdx.x;
  const int w = t >> 6, l = t & 63;
  const int lm = l & 15, quad = l >> 4;
  const int wm = (w >> 1) * 32, wn = (w & 1) * 64;
  const int m0 = by * BM, n0 = bx * BN;

  // staging: 8 lanes per 32-elem row; 32 rows/pass; A 2 passes, W 4 passes
  const int srow = t >> 3;        // 0..31
  const int scol = (t & 7) * 4;   // 0,4,..,28

  f32x4 acc[2][4] = {};
  f16x4 av[2], wv[4];
  // prologue: K-step 0 into regs
#pragma unroll
  for (int p = 0; p < 2; ++p)
    av[p] = load4h(&A[(size_t)(m0 + srow + p * 32) * K + scol]);
#pragma unroll
  for (int p = 0; p < 4; ++p)
    wv[p] = load4h(&W[(size_t)(n0 + srow + p * 32) * K + scol]);

  int cur = 0;
  for (int k0 = 0; k0 < K; k0 += 32) {
    _Float16* as = &As[cur * BM * GAP];
    _Float16* ws = &Ws[cur * BN * GAP];
#pragma unroll
    for (int p = 0; p < 2; ++p)
      *(f16x4*)&as[(srow + p * 32) * GAP + scol] = av[p];
#pragma unroll
    for (int p = 0; p < 4; ++p)
      *(f16x4*)&ws[(srow + p * 32) * GAP + scol] = wv[p];
    __syncthreads();
    // issue next K-step's loads; latency hides under frag reads + MFMA
    if (k0 + 32 < K) {
#pragma unroll
      for (int p = 0; p < 2; ++p)
        av[p] = load4h(&A[(size_t)(m0 + srow + p * 32) * K + k0 + 32 + scol]);
#pragma unroll
      for (int p = 0; p < 4; ++p)
        wv[p] = load4h(&W[(size_t)(n0 + srow + p * 32) * K + k0 + 32 + scol]);
    }

    f16x8 af[2], bf[4];
#pragma unroll
    for (int i = 0; i < 2; ++i)
      af[i] = *(const f16x8*)&as[(wm + i * 16 + lm) * GAP + quad * 8];
#pragma unroll
    for (int j = 0; j < 4; ++j)
      bf[j] = *(const f16x8*)&ws[(wn + j * 16 + lm) * GAP + quad * 8];
#pragma unroll
    for (int i = 0; i < 2; ++i)
#pragma unroll
      for (int j = 0; j < 4; ++j)
        acc[i][j] =
            __builtin_amdgcn_mfma_f32_16x16x32_f16(af[i], bf[j], acc[i][j], 0, 0, 0);
    cur ^= 1;
  }

  // C/D frag: lane holds D[row=quad*4+r][col=lm] per 16x16 tile
#pragma unroll
  for (int i = 0; i < 2; ++i)
#pragma unroll
    for (int r = 0; r < 4; ++r) {
      size_t row = (size_t)(m0 + wm + i * 16 + quad * 4 + r) * N;
#pragma unroll
      for (int j = 0; j < 4; ++j)
        store1(&C[row + n0 + wn + j * 16 + lm], acc[i][j][r]);
    }
}

// ---------- RoPE in place on fp16 [B*T, H, 64]; position = row % T ----------
// (used for K only; Q-rope is fused into attn_mfma's register load)
__global__ void rope_kernel(__half* __restrict__ X, int T, int H, int total_pairs) {
  int idx = blockIdx.x * blockDim.x + threadIdx.x;
  if (idx >= total_pairs) return;
  int i   = idx & 31;
  int h   = (idx >> 5) % H;
  int row = idx / (32 * H);
  int tpos = row % T;
  __half* p = X + ((size_t)row * H + h) * DK;
  // 10000^(-i/32) = exp2(-i * log2(10000)/32)
  float inv = exp2f((float)i * -0.41524101186091403f);
  float ang = (float)tpos * inv;
  float c, s;
  sincosf(ang, &s, &c);
  float x1 = __half2float(p[i]), x2 = __half2float(p[i + 32]);
  p[i]      = __float2half(x1 * c - x2 * s);
  p[i + 32] = __float2half(x2 * c + x1 * s);
}

// ---------- MFMA flash attention, 32x32 frags, swapped QK^T ----------
// (R10 structure; R12: vmax reduce via v_max3 tree -- 8 ops vs 15.)
#define AP 72  // LDS pitch (f16): 144B rows -> b128-aligned, balanced banks
#define C2 0.18033688011112042f  // 0.125 * log2(e)
#define RLOG2 -0.41524101186091403f  // -log2(10000)/32
__global__ __launch_bounds__(256, 3) void attn_mfma(const __half* Q,
                                                    const __half* __restrict__ K,
                                                    const __half* __restrict__ V,
                                                    __half* O) {
  __shared__ _Float16 Ks[64 * AP];        // [key][d]
  __shared__ _Float16 Vt[64 * AP];        // [d][key]
  const int t = threadIdx.x;
  const int w = t >> 6, l = t & 63;
  const int lq = l & 31, hi = l >> 5;
  const int qt = blockIdx.x, h = blockIdx.y, b = blockIdx.z;
  const int kvh = h >> 2;

  // Q B-frags (registers, whole kernel): aq[kc] = Q[qrow][kc*16+8*hi+j]
  const __half* qbase =
      Q + (((size_t)b * TQ + qt * 128 + w * 32 + lq) * NH + h) * DK;
  f16x8 aq[4];
#pragma unroll
  for (int kc = 0; kc < 4; ++kc)
    aq[kc] = *(const f16x8*)(qbase + kc * 16 + hi * 8);

  // fused RoPE on Q (in-register) + fold C2 scale: pair (d, d+32) =
  // (aq[kc][j], aq[kc+2][j]); after this, S^T is directly base-2 scores.
  {
    const float tpos = (float)(qt * 128 + w * 32 + lq);
#pragma unroll
    for (int kc = 0; kc < 2; ++kc)
#pragma unroll
      for (int j = 0; j < 8; ++j) {
        int d = kc * 16 + hi * 8 + j;
        float inv = exp2f((float)d * RLOG2);
        float ang = tpos * inv;
        float c, s;
        sincosf(ang, &s, &c);
        float x1 = (float)aq[kc][j], x2 = (float)aq[kc + 2][j];
        aq[kc][j]     = (_Float16)((x1 * c - x2 * s) * C2);
        aq[kc + 2][j] = (_Float16)((x2 * c + x1 * s) * C2);
      }
  }

  // staging: 2 x 16B units per thread for K and V each (64x64 f16 tiles)
  const int skey = t >> 3, sdseg = t & 7;          // K [key][d], +32 keys r=1
  const int vkey = t & 63, vdb0 = (t >> 6) * 8;    // V -> Vt [d][key], +32 d r=1
  const __half* kp0 =
      K + (((size_t)b * TKV + skey) * NKV + kvh) * DK + sdseg * 8;
  const __half* kp1 = kp0 + (size_t)32 * NKV * DK;
  const __half* vp0 =
      V + (((size_t)b * TKV + vkey) * NKV + kvh) * DK + vdb0;
  const __half* vp1 = vp0 + 32;
  const size_t kstep = (size_t)64 * NKV * DK;  // 64 keys forward

  f16x8 kpre0 = *(const f16x8*)kp0, kpre1 = *(const f16x8*)kp1;
  f16x8 vpre0 = *(const f16x8*)vp0, vpre1 = *(const f16x8*)vp1;

  f32x16 o_acc[2];
#pragma unroll
  for (int i = 0; i < 16; ++i) { o_acc[0][i] = 0.f; o_acc[1][i] = 0.f; }
  float m_run = -1e30f, l_run = 0.0f;  // column space (q = lq)

  for (int ck = 0; ck < TKV / 64; ++ck) {
    __syncthreads();  // prior chunk's Ks/Vt reads done
    *(f16x8*)&Ks[skey * AP + sdseg * 8] = kpre0;
    *(f16x8*)&Ks[(skey + 32) * AP + sdseg * 8] = kpre1;
#pragma unroll
    for (int j = 0; j < 8; ++j) {
      Vt[(vdb0 + j) * AP + vkey] = vpre0[j];
      Vt[(vdb0 + 32 + j) * AP + vkey] = vpre1[j];
    }
    __syncthreads();
    // T14: issue next chunk's loads now; latency hides under compute below
    if (ck + 1 < TKV / 64) {
      size_t off = (size_t)(ck + 1) * kstep;
      kpre0 = *(const f16x8*)(kp0 + off);
      kpre1 = *(const f16x8*)(kp1 + off);
      vpre0 = *(const f16x8*)(vp0 + off);
      vpre1 = *(const f16x8*)(vp1 + off);
    }

#pragma unroll
    for (int tile = 0; tile < 2; ++tile) {
      // S^T = K Q^T for keys [tile*32, +32) x 32 q-cols
      f32x16 st;
#pragma unroll
      for (int i = 0; i < 16; ++i) st[i] = 0.f;
      __builtin_amdgcn_s_setprio(1);
#pragma unroll
      for (int kc = 0; kc < 4; ++kc) {
        f16x8 ak =
            *(const f16x8*)&Ks[(tile * 32 + lq) * AP + kc * 16 + hi * 8];
        st = __builtin_amdgcn_mfma_f32_32x32x16_f16(ak, aq[kc], st, 0, 0, 0);
      }
      __builtin_amdgcn_s_setprio(0);

      // column max (q = lq): v_max3 tree (8 ops), then swap halves
      float vmax = fmax3(st[0], st[1], st[2]);
      vmax = fmax3(vmax, st[3], st[4]);
      vmax = fmax3(vmax, st[5], st[6]);
      vmax = fmax3(vmax, st[7], st[8]);
      vmax = fmax3(vmax, st[9], st[10]);
      vmax = fmax3(vmax, st[11], st[12]);
      vmax = fmax3(vmax, st[13], st[14]);
      vmax = fmaxf(vmax, st[15]);
      vmax = fmaxf(vmax, __shfl_xor(vmax, 32));

      // T13 defer-rescale: only pay when max grew past THR
      if (!__all(vmax - m_run <= 8.0f)) {
        float m_new = fmaxf(m_run, vmax);
        float alpha = exp2f(m_run - m_new);  // column space
        m_run = m_new;
        l_run *= alpha;
#pragma unroll
        for (int reg = 0; reg < 16; ++reg) {
          int row = (reg & 3) + 8 * (reg >> 2) + 4 * hi;
          float ar = __shfl(alpha, row);     // alpha for q-row of this reg
          o_acc[0][reg] *= ar;
          o_acc[1][reg] *= ar;
        }
      }

      // P = 2^(st - m): pack to f16 pairs; l_run += column sum
      unsigned q16u[8];
      float psum = 0.0f;
#pragma unroll
      for (int rr = 0; rr < 8; ++rr) {
        float p0 = exp2f(st[2 * rr] - m_run);
        float p1 = exp2f(st[2 * rr + 1] - m_run);
        psum += p0 + p1;
        q16u[rr] = pack2h(p0, p1);
      }
      psum += __shfl_xor(psum, 32);  // other half's 16 keys
      l_run += psum;

      // Redistribute P^T (column space) -> PV A-frags (row space); O += P V
      __builtin_amdgcn_s_setprio(1);
#pragma unroll
      for (int kb = 0; kb < 2; ++kb) {
        const int base = kb * 4;
        union { unsigned u[4]; f16x8 v; } ap;
#pragma unroll
        for (int c = 0; c < 2; ++c) {
          unsigned R0 = q16u[base + c];       // reg wanted by hi_t=0
          unsigned R1 = q16u[base + 2 + c];   // reg wanted by hi_t=1
          unsigned Z = hi ? R0 : R1;          // what my partner wants
          unsigned Xp = __shfl_xor(Z, 32);    // partner's Z (what I want)
          ap.u[c]     = hi ? Xp : R0;         // from hi=0 half
          ap.u[c + 2] = hi ? R1 : Xp;         // from hi=1 half
        }
#pragma unroll
        for (int nt = 0; nt < 2; ++nt) {
          f16x8 bv = *(const f16x8*)&Vt[(nt * 32 + lq) * AP + tile * 32 +
                                        kb * 16 + hi * 8];
          o_acc[nt] =
              __builtin_amdgcn_mfma_f32_32x32x16_f16(ap.v, bv, o_acc[nt], 0, 0, 0);
        }
      }
      __builtin_amdgcn_s_setprio(0);
    }
  }

  // epilogue: row = (reg&3)+8*(reg>>2)+4*hi, cols d = nt*32 + lq;
  // l_run is column-space -> fetch per-row value by lane shuffle.
#pragma unroll
  for (int reg = 0; reg < 16; ++reg) {
    int row = (reg & 3) + 8 * (reg >> 2) + 4 * hi;
    float inv = 1.0f / __shfl(l_run, row);
    size_t orow =
        (((size_t)b * TQ + qt * 128 + w * 32 + row) * NH + h) * DK;
    O[orow + lq]      = __float2half(o_acc[0][reg] * inv);
    O[orow + 32 + lq] = __float2half(o_acc[1][reg] * inv);
  }
}

extern "C" void kernel_launch(void* const* d_in, const int* in_sizes, int n_in,
                              void* d_out, int out_size, void* d_ws, size_t ws_size,
                              hipStream_t stream) {
  // ---- Input mapping via in_sizes pattern (dict vs sorted-key order) ----
  int iq, ikv, iwq, iwk, iwv, iwo;
  bool ok = true;
  if (n_in >= 8 && in_sizes[0] == 8388608 && in_sizes[1] == 8388608) {
    iq = 0; ikv = 1; iwq = 4; iwk = 5; iwv = 6; iwo = 7;          // dict order
  } else if (n_in >= 8 && in_sizes[0] == 8388608 && in_sizes[1] == 8192) {
    ikv = 0; iq = 2; iwk = 4; iwo = 5; iwq = 6; iwv = 7;          // sorted keys
  } else if (n_in == 6 && in_sizes[2] == 1048576) {
    iq = 0; ikv = 1; iwq = 2; iwk = 3; iwv = 4; iwo = 5;          // dict, no masks
  } else if (n_in == 6 && in_sizes[2] == 262144) {
    ikv = 0; iq = 1; iwk = 2; iwo = 3; iwq = 4; iwv = 5;          // sorted, no masks
  } else {
    ok = false; iq = ikv = iwq = iwk = iwv = iwo = 0;
  }

  const size_t nQ  = (size_t)B_ * TQ * DM;
  const size_t nKV = (size_t)B_ * TKV * NKV * DK;
  const size_t need = (nQ + 2 * nKV) * sizeof(__half);  // 24 MB
  if (!ok || ws_size < need) {
    zero_out_kernel<<<(out_size + 255) / 256, 256, 0, stream>>>((float*)d_out,
                                                                out_size);
    return;
  }

  const float* query     = (const float*)d_in[iq];
  const float* key_value = (const float*)d_in[ikv];
  const float* w_q   = (const float*)d_in[iwq];
  const float* w_k   = (const float*)d_in[iwk];
  const float* w_v   = (const float*)d_in[iwv];
  const float* w_out = (const float*)d_in[iwo];
  float* out = (float*)d_out;

  __half* Qh = (__half*)d_ws;
  __half* Kh = Qh + nQ;
  __half* Vh = Kh + nKV;

  dim3 blk(256);
  // Fused Q/K/V projections, one 1536-block launch:
  // bid<1024: Q-proj (M=8192,N=1024); +256: K-proj; +256: V-proj (N=256).
  gemm_proj<<<dim3(1536), blk, 0, stream>>>(query, key_value, w_q, w_k, w_v,
                                            Qh, Kh, Vh, DM, NKV * DK, DM);
  int pk = B_ * TKV * NKV * 32;
  rope_kernel<<<(pk + 255) / 256, blk, 0, stream>>>(Kh, TKV, NKV, pk);
  // MFMA flash attention (32x32 frags, P-in-register, fused Q-rope)
  attn_mfma<<<dim3(TQ / 128, NH, B_), dim3(256), 0, stream>>>(Qh, Kh, Vh, Qh);
  // Output projection: M=8192, N=1024, K=1024, fp32 out (f16 A input);
  // grid 1024 -> z=0 path only.
  gemm_proj<<<dim3(1024), blk, 0, stream>>>(Qh, Qh, w_out, w_out, w_out,
                                            out, out, out, DM, DM, DM);
}